// Round 1
// baseline (533.803 us; speedup 1.0000x reference)
//
#include <hip/hip_runtime.h>

#define N_NODES 50000
#define E_EDGES 800000
#define D_IN    128
#define ED_IN   32
#define H_HID   16
#define D_OUT2  128
#define D_CAT   144   // D_IN + H_HID
#define EPB     64    // edges per block in edge kernel
#define BM      128   // rows per block in GEMM kernels

__device__ __forceinline__ float gelu_exact(float v) {
    return 0.5f * v * (1.0f + erff(v * 0.70710678118654752f));
}
__device__ __forceinline__ float4 ld4(const float* p) { return *reinterpret_cast<const float4*>(p); }
__device__ __forceinline__ void st4(float* p, float4 v) { *reinterpret_cast<float4*>(p) = v; }

// M = (1+eps) * ego_W @ W1   [128,128]
__global__ void k_prep_M(const float* __restrict__ egoW, const float* __restrict__ W1,
                         const float* __restrict__ eps, float* __restrict__ M) {
    int d = blockIdx.x;   // 0..127
    int c = threadIdx.x;  // 0..127
    float acc = 0.f;
    for (int j = 0; j < D_CAT; ++j)
        acc = fmaf(egoW[d * D_CAT + j], W1[j * D_OUT2 + c], acc);
    M[d * D_OUT2 + c] = (1.0f + eps[0]) * acc;
}

// Fused edge MLP + scatter-add into agg[N,144]
__global__ __launch_bounds__(256) void k_edge(const float* __restrict__ x,
        const int* __restrict__ eidx, const float* __restrict__ ef,
        const float* __restrict__ eW1, const float* __restrict__ eb1,
        const float* __restrict__ eW2, const float* __restrict__ eb2,
        float* __restrict__ agg) {
    __shared__ float efs[EPB][ED_IN];
    __shared__ float hs[EPB][H_HID];
    __shared__ float es[EPB][H_HID];
    __shared__ int   sidx[EPB];
    __shared__ int   didx[EPB];
    __shared__ float w1s[ED_IN][H_HID];
    __shared__ float w2s[H_HID][H_HID];
    __shared__ float b1s[H_HID];
    __shared__ float b2s[H_HID];

    const int t = threadIdx.x;
    const int e0 = blockIdx.x * EPB;
    const int ne = min(EPB, E_EDGES - e0);

    // stage tiny weights
    for (int i = t; i < ED_IN * H_HID; i += 256) w1s[i / H_HID][i % H_HID] = eW1[i];
    if (t < H_HID * H_HID) w2s[t / H_HID][t % H_HID] = eW2[t];
    if (t < H_HID) { b1s[t] = eb1[t]; b2s[t] = eb2[t]; }
    // stage indices (int32 per harness convention)
    if (t < EPB)              { int le = t;      if (le < ne) sidx[le] = eidx[e0 + le]; }
    else if (t < 2 * EPB)     { int le = t - EPB; if (le < ne) didx[le] = eidx[E_EDGES + e0 + le]; }
    // stage edge features: EPB*32 floats = 512 float4
    #pragma unroll
    for (int i = 0; i < 2; ++i) {
        int q = t + 256 * i;          // 0..511
        int le = q >> 3;              // 8 float4 per row
        int coff = (q & 7) * 4;
        float4 v = make_float4(0.f, 0.f, 0.f, 0.f);
        if (le < ne) v = ld4(ef + (e0 + le) * ED_IN + coff);
        st4(&efs[le][coff], v);
    }
    __syncthreads();

    // layer 1: 4 threads per edge, 4 hidden units each
    {
        int le = t >> 2, p = t & 3;
        if (le < ne) {
            #pragma unroll
            for (int jj = 0; jj < 4; ++jj) {
                int j = p * 4 + jj;
                float acc = b1s[j];
                #pragma unroll
                for (int k = 0; k < ED_IN; ++k) acc = fmaf(efs[le][k], w1s[k][j], acc);
                hs[le][j] = gelu_exact(acc);
            }
        }
    }
    __syncthreads();
    // layer 2
    {
        int le = t >> 2, p = t & 3;
        if (le < ne) {
            #pragma unroll
            for (int cc = 0; cc < 4; ++cc) {
                int c = p * 4 + cc;
                float acc = b2s[c];
                #pragma unroll
                for (int k = 0; k < H_HID; ++k) acc = fmaf(hs[le][k], w2s[k][c], acc);
                es[le][c] = acc;
            }
        }
    }
    __syncthreads();

    // scatter: one wave per 16 edges; lanes cover channels
    const int w = t >> 6, lane = t & 63;
    #pragma unroll 2
    for (int i = 0; i < 16; ++i) {
        int le = w * 16 + i;
        if (le >= ne) break;
        int s = sidx[le], d = didx[le];
        const float* xr = x + s * D_IN;
        float* ar = agg + d * D_CAT;
        float v0 = xr[lane];
        float v1 = xr[64 + lane];
        unsafeAtomicAdd(ar + lane, v0);
        unsafeAtomicAdd(ar + 64 + lane, v1);
        if (lane < H_HID) unsafeAtomicAdd(ar + D_IN + lane, es[le][lane]);
    }
}

// h = x @ M + agg @ W1   (b1 cancels in BN); also accumulate col sums / sumsq
__global__ __launch_bounds__(256) void k_gemm1(const float* __restrict__ x,
        const float* __restrict__ agg, const float* __restrict__ M,
        const float* __restrict__ W1, float* __restrict__ h, float* __restrict__ stats) {
    __shared__ float As[128][20];    // 16 + pad 4 (keeps float4 alignment)
    __shared__ float Bs[16][132];
    __shared__ float red0[128];
    __shared__ float red1[128];
    const int t = threadIdx.x;
    const int row0 = blockIdx.x * BM;
    const int rg = t >> 4, cg = t & 15;
    float acc[8][8];
    #pragma unroll
    for (int i = 0; i < 8; ++i)
        #pragma unroll
        for (int j = 0; j < 8; ++j) acc[i][j] = 0.f;

    #pragma unroll 1
    for (int ch = 0; ch < 17; ++ch) {
        const float* Ap; const float* Bp; int lda, k0;
        if (ch < 8) { Ap = x;   lda = D_IN;  k0 = ch * 16;       Bp = M  + k0 * 128; }
        else        { Ap = agg; lda = D_CAT; k0 = (ch - 8) * 16; Bp = W1 + k0 * 128; }
        #pragma unroll
        for (int i = 0; i < 2; ++i) {                 // A tile: 128x16
            int q = t + 256 * i;
            int row = q >> 2, coff = (q & 3) * 4;
            int r = row0 + row;
            float4 v = make_float4(0.f, 0.f, 0.f, 0.f);
            if (r < N_NODES) v = ld4(Ap + r * lda + k0 + coff);
            st4(&As[row][coff], v);
        }
        #pragma unroll
        for (int i = 0; i < 2; ++i) {                 // B tile: 16x128
            int q = t + 256 * i;
            int row = q >> 5, coff = (q & 31) * 4;
            st4(&Bs[row][coff], ld4(Bp + row * 128 + coff));
        }
        __syncthreads();
        #pragma unroll
        for (int kk = 0; kk < 16; ++kk) {
            float a[8];
            #pragma unroll
            for (int i = 0; i < 8; ++i) a[i] = As[rg * 8 + i][kk];
            float4 b0 = ld4(&Bs[kk][cg * 8]);
            float4 b1v = ld4(&Bs[kk][cg * 8 + 4]);
            float b[8] = {b0.x, b0.y, b0.z, b0.w, b1v.x, b1v.y, b1v.z, b1v.w};
            #pragma unroll
            for (int i = 0; i < 8; ++i)
                #pragma unroll
                for (int j = 0; j < 8; ++j)
                    acc[i][j] = fmaf(a[i], b[j], acc[i][j]);
        }
        __syncthreads();
    }

    if (t < 128) { red0[t] = 0.f; red1[t] = 0.f; }
    __syncthreads();
    float s0[8], s1[8];
    #pragma unroll
    for (int j = 0; j < 8; ++j) { s0[j] = 0.f; s1[j] = 0.f; }
    #pragma unroll
    for (int i = 0; i < 8; ++i) {
        int r = row0 + rg * 8 + i;
        if (r < N_NODES) {
            st4(h + r * 128 + cg * 8,     make_float4(acc[i][0], acc[i][1], acc[i][2], acc[i][3]));
            st4(h + r * 128 + cg * 8 + 4, make_float4(acc[i][4], acc[i][5], acc[i][6], acc[i][7]));
            #pragma unroll
            for (int j = 0; j < 8; ++j) { float v = acc[i][j]; s0[j] += v; s1[j] += v * v; }
        }
    }
    #pragma unroll
    for (int j = 0; j < 8; ++j) {
        atomicAdd(&red0[cg * 8 + j], s0[j]);
        atomicAdd(&red1[cg * 8 + j], s1[j]);
    }
    __syncthreads();
    if (t < 128) {
        unsafeAtomicAdd(stats + t,       red0[t]);
        unsafeAtomicAdd(stats + 128 + t, red1[t]);
    }
}

// BN affine params: a = gamma*rsqrt(var+eps), b = beta - mu*a
__global__ void k_bnparam(const float* __restrict__ stats, const float* __restrict__ gamma,
                          const float* __restrict__ beta, float* __restrict__ ab) {
    int c = threadIdx.x;
    float mu  = stats[c] * (1.0f / N_NODES);
    float var = stats[128 + c] * (1.0f / N_NODES) - mu * mu;
    float a = gamma[c] * rsqrtf(var + 1e-5f);
    ab[c] = a;
    ab[128 + c] = beta[c] - mu * a;
}

// out = GELU(a*h+b) @ W2 + b2 ; h lives in d_out (in-place safe: block reads only its own rows)
__global__ __launch_bounds__(256) void k_gemm2(const float* __restrict__ h,
        const float* __restrict__ ab, const float* __restrict__ W2,
        const float* __restrict__ b2, float* __restrict__ out) {
    __shared__ float gs[128][128];
    __shared__ float Bs[16][132];
    __shared__ float sa[128], sb[128], sc[128];
    const int t = threadIdx.x;
    const int row0 = blockIdx.x * BM;
    if (t < 128) { sa[t] = ab[t]; sb[t] = ab[128 + t]; sc[t] = b2[t]; }
    __syncthreads();
    #pragma unroll
    for (int i = 0; i < 16; ++i) {                    // stage + affine + GELU
        int q = t + 256 * i;                          // 0..4095
        int row = q >> 5, coff = (q & 31) * 4;
        int r = row0 + row;
        float4 v = make_float4(0.f, 0.f, 0.f, 0.f);
        if (r < N_NODES) v = ld4(h + r * 128 + coff);
        v.x = gelu_exact(fmaf(sa[coff],     v.x, sb[coff]));
        v.y = gelu_exact(fmaf(sa[coff + 1], v.y, sb[coff + 1]));
        v.z = gelu_exact(fmaf(sa[coff + 2], v.z, sb[coff + 2]));
        v.w = gelu_exact(fmaf(sa[coff + 3], v.w, sb[coff + 3]));
        st4(&gs[row][coff], v);
    }
    __syncthreads();
    const int rg = t >> 4, cg = t & 15;
    float acc[8][8];
    #pragma unroll
    for (int i = 0; i < 8; ++i)
        #pragma unroll
        for (int j = 0; j < 8; ++j) acc[i][j] = 0.f;
    #pragma unroll 1
    for (int ch = 0; ch < 8; ++ch) {
        #pragma unroll
        for (int i = 0; i < 2; ++i) {
            int q = t + 256 * i;
            int row = q >> 5, coff = (q & 31) * 4;
            st4(&Bs[row][coff], ld4(W2 + (ch * 16 + row) * 128 + coff));
        }
        __syncthreads();
        #pragma unroll
        for (int kk = 0; kk < 16; ++kk) {
            int k = ch * 16 + kk;
            float a[8];
            #pragma unroll
            for (int i = 0; i < 8; ++i) a[i] = gs[rg * 8 + i][k];
            float4 b0 = ld4(&Bs[kk][cg * 8]);
            float4 b1v = ld4(&Bs[kk][cg * 8 + 4]);
            float b[8] = {b0.x, b0.y, b0.z, b0.w, b1v.x, b1v.y, b1v.z, b1v.w};
            #pragma unroll
            for (int i = 0; i < 8; ++i)
                #pragma unroll
                for (int j = 0; j < 8; ++j)
                    acc[i][j] = fmaf(a[i], b[j], acc[i][j]);
        }
        __syncthreads();
    }
    #pragma unroll
    for (int i = 0; i < 8; ++i) {
        int r = row0 + rg * 8 + i;
        if (r < N_NODES) {
            st4(out + r * 128 + cg * 8,
                make_float4(acc[i][0] + sc[cg * 8], acc[i][1] + sc[cg * 8 + 1],
                            acc[i][2] + sc[cg * 8 + 2], acc[i][3] + sc[cg * 8 + 3]));
            st4(out + r * 128 + cg * 8 + 4,
                make_float4(acc[i][4] + sc[cg * 8 + 4], acc[i][5] + sc[cg * 8 + 5],
                            acc[i][6] + sc[cg * 8 + 6], acc[i][7] + sc[cg * 8 + 7]));
        }
    }
}

extern "C" void kernel_launch(void* const* d_in, const int* in_sizes, int n_in,
                              void* d_out, int out_size, void* d_ws, size_t ws_size,
                              hipStream_t stream) {
    const float* x     = (const float*)d_in[0];
    const int*   eidx  = (const int*)d_in[1];
    const float* ef    = (const float*)d_in[2];
    const float* eW1   = (const float*)d_in[3];
    const float* eb1   = (const float*)d_in[4];
    const float* eW2   = (const float*)d_in[5];
    const float* eb2   = (const float*)d_in[6];
    const float* egoW  = (const float*)d_in[7];
    const float* eps   = (const float*)d_in[8];
    const float* W1    = (const float*)d_in[9];
    // d_in[10] = b1: cancels in BatchNorm (uniform shift), intentionally unused
    const float* gamma = (const float*)d_in[11];
    const float* beta  = (const float*)d_in[12];
    const float* W2    = (const float*)d_in[13];
    const float* b2    = (const float*)d_in[14];
    float* out = (float*)d_out;

    char* ws = (char*)d_ws;
    float* agg   = (float*)ws;                           // N*144 f32 = 28.8 MB
    float* stats = (float*)(ws + 28800000);              // 256 f32
    float* M     = (float*)(ws + 28801024);              // 128*128 f32
    float* ab    = (float*)(ws + 28801024 + 65536);      // 256 f32
    float* h     = out;                                  // h staged in d_out (in-place safe)

    hipMemsetAsync(agg, 0, 28801024, stream);            // zero agg + stats each call
    k_prep_M<<<dim3(128), dim3(128), 0, stream>>>(egoW, W1, eps, M);
    k_edge<<<dim3(E_EDGES / EPB), dim3(256), 0, stream>>>(x, eidx, ef, eW1, eb1, eW2, eb2, agg);
    k_gemm1<<<dim3((N_NODES + BM - 1) / BM), dim3(256), 0, stream>>>(x, agg, M, W1, h, stats);
    k_bnparam<<<dim3(1), dim3(128), 0, stream>>>(stats, gamma, beta, ab);
    k_gemm2<<<dim3((N_NODES + BM - 1) / BM), dim3(256), 0, stream>>>(h, ab, W2, b2, out);
}

// Round 2
// 443.232 us; speedup vs baseline: 1.2043x; 1.2043x over previous
//
#include <hip/hip_runtime.h>

#define N_NODES 50000
#define E_EDGES 800000
#define D_IN    128
#define ED_IN   32
#define H_HID   16
#define D_OUT2  128
#define D_CAT   144   // D_IN + H_HID
#define EPB     64    // edges per block in edge kernel
#define BM      128   // rows per block in GEMM kernels

__device__ __forceinline__ float gelu_exact(float v) {
    return 0.5f * v * (1.0f + erff(v * 0.70710678118654752f));
}
__device__ __forceinline__ float4 ld4(const float* p) { return *reinterpret_cast<const float4*>(p); }
__device__ __forceinline__ void st4(float* p, float4 v) { *reinterpret_cast<float4*>(p) = v; }
__device__ __forceinline__ unsigned short f2bf(float f) {   // RNE bf16
    unsigned u = __float_as_uint(f);
    return (unsigned short)((u + 0x7FFFu + ((u >> 16) & 1u)) >> 16);
}
__device__ __forceinline__ float bf2f(unsigned short u) {
    return __uint_as_float(((unsigned)u) << 16);
}

// M = (1+eps) * ego_W @ W1   [128,128]
__global__ void k_prep_M(const float* __restrict__ egoW, const float* __restrict__ W1,
                         const float* __restrict__ eps, float* __restrict__ M) {
    int d = blockIdx.x;   // 0..127
    int c = threadIdx.x;  // 0..127
    float acc = 0.f;
    for (int j = 0; j < D_CAT; ++j)
        acc = fmaf(egoW[d * D_CAT + j], W1[j * D_OUT2 + c], acc);
    M[d * D_OUT2 + c] = (1.0f + eps[0]) * acc;
}

// degree histogram over dst
__global__ __launch_bounds__(256) void k_hist(const int* __restrict__ dst, int* __restrict__ deg) {
    int e = blockIdx.x * 256 + threadIdx.x;
    if (e < E_EDGES) atomicAdd(&deg[dst[e]], 1);
}

// single-block exclusive scan: cursor holds deg on entry; writes rowptr and rewrites cursor=prefix
__global__ __launch_bounds__(1024) void k_scan(int* __restrict__ cursor, int* __restrict__ rowptr) {
    const int t = threadIdx.x;
    const int CH = 50;                       // 1024*50 = 51200 >= 50000
    const int i0 = t * CH;
    int vals[CH];
    int sum = 0;
    #pragma unroll
    for (int i = 0; i < CH; ++i) {
        int idx = i0 + i;
        int v = (idx < N_NODES) ? cursor[idx] : 0;
        vals[i] = sum;                       // exclusive within chunk
        sum += v;
    }
    __shared__ int tot[1024];
    tot[t] = sum;
    __syncthreads();
    for (int off = 1; off < 1024; off <<= 1) {
        int v = (t >= off) ? tot[t - off] : 0;
        __syncthreads();
        tot[t] += v;
        __syncthreads();
    }
    int base = tot[t] - sum;                 // exclusive across chunks
    #pragma unroll
    for (int i = 0; i < CH; ++i) {
        int idx = i0 + i;
        if (idx < N_NODES) { int p = base + vals[i]; rowptr[idx] = p; cursor[idx] = p; }
    }
    if (t == 0) rowptr[N_NODES] = E_EDGES;
}

// Fused edge MLP + sorted placement: 1 int atomic per edge; writes src + bf16 e_emb at sorted pos
__global__ __launch_bounds__(256) void k_edge(const float* __restrict__ ef,
        const int* __restrict__ eidx,
        const float* __restrict__ eW1, const float* __restrict__ eb1,
        const float* __restrict__ eW2, const float* __restrict__ eb2,
        int* __restrict__ cursor, int* __restrict__ srcs_s,
        unsigned short* __restrict__ esort) {
    __shared__ float efs[EPB][ED_IN];
    __shared__ float hs[EPB][H_HID];
    __shared__ float es[EPB][H_HID];
    __shared__ int   sidx[EPB];
    __shared__ int   didx[EPB];
    __shared__ int   poss[EPB];
    __shared__ float w1s[ED_IN][H_HID];
    __shared__ float w2s[H_HID][H_HID];
    __shared__ float b1s[H_HID];
    __shared__ float b2s[H_HID];

    const int t = threadIdx.x;
    const int e0 = blockIdx.x * EPB;
    const int ne = min(EPB, E_EDGES - e0);

    for (int i = t; i < ED_IN * H_HID; i += 256) w1s[i / H_HID][i % H_HID] = eW1[i];
    if (t < H_HID * H_HID) w2s[t / H_HID][t % H_HID] = eW2[t];
    if (t < H_HID) { b1s[t] = eb1[t]; b2s[t] = eb2[t]; }
    if (t < EPB)              { int le = t;       if (le < ne) sidx[le] = eidx[e0 + le]; }
    else if (t < 2 * EPB)     { int le = t - EPB; if (le < ne) didx[le] = eidx[E_EDGES + e0 + le]; }
    #pragma unroll
    for (int i = 0; i < 2; ++i) {
        int q = t + 256 * i;
        int le = q >> 3, coff = (q & 7) * 4;
        float4 v = make_float4(0.f, 0.f, 0.f, 0.f);
        if (le < ne) v = ld4(ef + (e0 + le) * ED_IN + coff);
        st4(&efs[le][coff], v);
    }
    __syncthreads();

    {   // layer 1: 4 threads/edge, 4 hidden each
        int le = t >> 2, p = t & 3;
        if (le < ne) {
            #pragma unroll
            for (int jj = 0; jj < 4; ++jj) {
                int j = p * 4 + jj;
                float acc = b1s[j];
                #pragma unroll
                for (int k = 0; k < ED_IN; ++k) acc = fmaf(efs[le][k], w1s[k][j], acc);
                hs[le][j] = gelu_exact(acc);
            }
        }
    }
    __syncthreads();
    {   // layer 2
        int le = t >> 2, p = t & 3;
        if (le < ne) {
            #pragma unroll
            for (int cc = 0; cc < 4; ++cc) {
                int c = p * 4 + cc;
                float acc = b2s[c];
                #pragma unroll
                for (int k = 0; k < H_HID; ++k) acc = fmaf(hs[le][k], w2s[k][c], acc);
                es[le][c] = acc;
            }
        }
    }
    __syncthreads();

    if (t < EPB && t < ne) poss[t] = atomicAdd(&cursor[didx[t]], 1);
    __syncthreads();

    {   // write src + packed bf16 e_emb to sorted position (4 threads/edge, 8B each)
        int le = t >> 2, p = t & 3;
        if (le < ne) {
            int pos = poss[le];
            if (p == 0) srcs_s[pos] = sidx[le];
            ushort4 w;
            w.x = f2bf(es[le][p * 4 + 0]);
            w.y = f2bf(es[le][p * 4 + 1]);
            w.z = f2bf(es[le][p * 4 + 2]);
            w.w = f2bf(es[le][p * 4 + 3]);
            *reinterpret_cast<ushort4*>(esort + (size_t)pos * 16 + p * 4) = w;
        }
    }
}

// CSR aggregation: one wave per node; lanes cover channels; no atomics, one write per agg row
__global__ __launch_bounds__(256) void k_agg(const float* __restrict__ x,
        const int* __restrict__ rowptr, const int* __restrict__ srcs_s,
        const unsigned short* __restrict__ esort, float* __restrict__ agg) {
    const int wave = threadIdx.x >> 6, lane = threadIdx.x & 63;
    const int n = blockIdx.x * 4 + wave;           // grid 12500 -> exactly 50000
    const int beg = rowptr[n], end = rowptr[n + 1];
    float a0 = 0.f, a1 = 0.f, ae = 0.f;
    for (int base = beg; base < end; base += 64) {
        int m = min(64, end - base);
        int sv = (base + lane < end) ? srcs_s[base + lane] : 0;
        for (int j = 0; j < m; ++j) {
            int s = __shfl(sv, j);
            float2 v = *reinterpret_cast<const float2*>(x + (size_t)s * D_IN + 2 * lane);
            a0 += v.x; a1 += v.y;
            if (lane < H_HID) ae += bf2f(esort[(size_t)(base + j) * 16 + lane]);
        }
    }
    float* ar = agg + (size_t)n * D_CAT;
    *reinterpret_cast<float2*>(ar + 2 * lane) = make_float2(a0, a1);
    if (lane < H_HID) ar[D_IN + lane] = ae;
}

// h = x @ M + agg @ W1   (b1 cancels in BN); also accumulate col sums / sumsq
__global__ __launch_bounds__(256) void k_gemm1(const float* __restrict__ x,
        const float* __restrict__ agg, const float* __restrict__ M,
        const float* __restrict__ W1, float* __restrict__ h, float* __restrict__ stats) {
    __shared__ float As[128][20];
    __shared__ float Bs[16][132];
    __shared__ float red0[128];
    __shared__ float red1[128];
    const int t = threadIdx.x;
    const int row0 = blockIdx.x * BM;
    const int rg = t >> 4, cg = t & 15;
    float acc[8][8];
    #pragma unroll
    for (int i = 0; i < 8; ++i)
        #pragma unroll
        for (int j = 0; j < 8; ++j) acc[i][j] = 0.f;

    #pragma unroll 1
    for (int ch = 0; ch < 17; ++ch) {
        const float* Ap; const float* Bp; int lda, k0;
        if (ch < 8) { Ap = x;   lda = D_IN;  k0 = ch * 16;       Bp = M  + k0 * 128; }
        else        { Ap = agg; lda = D_CAT; k0 = (ch - 8) * 16; Bp = W1 + k0 * 128; }
        #pragma unroll
        for (int i = 0; i < 2; ++i) {
            int q = t + 256 * i;
            int row = q >> 2, coff = (q & 3) * 4;
            int r = row0 + row;
            float4 v = make_float4(0.f, 0.f, 0.f, 0.f);
            if (r < N_NODES) v = ld4(Ap + (size_t)r * lda + k0 + coff);
            st4(&As[row][coff], v);
        }
        #pragma unroll
        for (int i = 0; i < 2; ++i) {
            int q = t + 256 * i;
            int row = q >> 5, coff = (q & 31) * 4;
            st4(&Bs[row][coff], ld4(Bp + row * 128 + coff));
        }
        __syncthreads();
        #pragma unroll
        for (int kk = 0; kk < 16; ++kk) {
            float a[8];
            #pragma unroll
            for (int i = 0; i < 8; ++i) a[i] = As[rg * 8 + i][kk];
            float4 b0 = ld4(&Bs[kk][cg * 8]);
            float4 b1v = ld4(&Bs[kk][cg * 8 + 4]);
            float b[8] = {b0.x, b0.y, b0.z, b0.w, b1v.x, b1v.y, b1v.z, b1v.w};
            #pragma unroll
            for (int i = 0; i < 8; ++i)
                #pragma unroll
                for (int j = 0; j < 8; ++j)
                    acc[i][j] = fmaf(a[i], b[j], acc[i][j]);
        }
        __syncthreads();
    }

    if (t < 128) { red0[t] = 0.f; red1[t] = 0.f; }
    __syncthreads();
    float s0[8], s1[8];
    #pragma unroll
    for (int j = 0; j < 8; ++j) { s0[j] = 0.f; s1[j] = 0.f; }
    #pragma unroll
    for (int i = 0; i < 8; ++i) {
        int r = row0 + rg * 8 + i;
        if (r < N_NODES) {
            st4(h + (size_t)r * 128 + cg * 8,     make_float4(acc[i][0], acc[i][1], acc[i][2], acc[i][3]));
            st4(h + (size_t)r * 128 + cg * 8 + 4, make_float4(acc[i][4], acc[i][5], acc[i][6], acc[i][7]));
            #pragma unroll
            for (int j = 0; j < 8; ++j) { float v = acc[i][j]; s0[j] += v; s1[j] += v * v; }
        }
    }
    #pragma unroll
    for (int j = 0; j < 8; ++j) {
        atomicAdd(&red0[cg * 8 + j], s0[j]);
        atomicAdd(&red1[cg * 8 + j], s1[j]);
    }
    __syncthreads();
    if (t < 128) {
        unsafeAtomicAdd(stats + t,       red0[t]);
        unsafeAtomicAdd(stats + 128 + t, red1[t]);
    }
}

// BN affine params: a = gamma*rsqrt(var+eps), b = beta - mu*a
__global__ void k_bnparam(const float* __restrict__ stats, const float* __restrict__ gamma,
                          const float* __restrict__ beta, float* __restrict__ ab) {
    int c = threadIdx.x;
    float mu  = stats[c] * (1.0f / N_NODES);
    float var = stats[128 + c] * (1.0f / N_NODES) - mu * mu;
    float a = gamma[c] * rsqrtf(var + 1e-5f);
    ab[c] = a;
    ab[128 + c] = beta[c] - mu * a;
}

// out = GELU(a*h+b) @ W2 + b2 ; h lives in d_out (in-place safe: block reads only its own rows)
__global__ __launch_bounds__(256) void k_gemm2(const float* __restrict__ h,
        const float* __restrict__ ab, const float* __restrict__ W2,
        const float* __restrict__ b2, float* __restrict__ out) {
    __shared__ float gs[128][128];
    __shared__ float Bs[16][132];
    __shared__ float sa[128], sb[128], sc[128];
    const int t = threadIdx.x;
    const int row0 = blockIdx.x * BM;
    if (t < 128) { sa[t] = ab[t]; sb[t] = ab[128 + t]; sc[t] = b2[t]; }
    __syncthreads();
    #pragma unroll
    for (int i = 0; i < 16; ++i) {
        int q = t + 256 * i;
        int row = q >> 5, coff = (q & 31) * 4;
        int r = row0 + row;
        float4 v = make_float4(0.f, 0.f, 0.f, 0.f);
        if (r < N_NODES) v = ld4(h + (size_t)r * 128 + coff);
        v.x = gelu_exact(fmaf(sa[coff],     v.x, sb[coff]));
        v.y = gelu_exact(fmaf(sa[coff + 1], v.y, sb[coff + 1]));
        v.z = gelu_exact(fmaf(sa[coff + 2], v.z, sb[coff + 2]));
        v.w = gelu_exact(fmaf(sa[coff + 3], v.w, sb[coff + 3]));
        st4(&gs[row][coff], v);
    }
    __syncthreads();
    const int rg = t >> 4, cg = t & 15;
    float acc[8][8];
    #pragma unroll
    for (int i = 0; i < 8; ++i)
        #pragma unroll
        for (int j = 0; j < 8; ++j) acc[i][j] = 0.f;
    #pragma unroll 1
    for (int ch = 0; ch < 8; ++ch) {
        #pragma unroll
        for (int i = 0; i < 2; ++i) {
            int q = t + 256 * i;
            int row = q >> 5, coff = (q & 31) * 4;
            st4(&Bs[row][coff], ld4(W2 + (ch * 16 + row) * 128 + coff));
        }
        __syncthreads();
        #pragma unroll
        for (int kk = 0; kk < 16; ++kk) {
            int k = ch * 16 + kk;
            float a[8];
            #pragma unroll
            for (int i = 0; i < 8; ++i) a[i] = gs[rg * 8 + i][k];
            float4 b0 = ld4(&Bs[kk][cg * 8]);
            float4 b1v = ld4(&Bs[kk][cg * 8 + 4]);
            float b[8] = {b0.x, b0.y, b0.z, b0.w, b1v.x, b1v.y, b1v.z, b1v.w};
            #pragma unroll
            for (int i = 0; i < 8; ++i)
                #pragma unroll
                for (int j = 0; j < 8; ++j)
                    acc[i][j] = fmaf(a[i], b[j], acc[i][j]);
        }
        __syncthreads();
    }
    #pragma unroll
    for (int i = 0; i < 8; ++i) {
        int r = row0 + rg * 8 + i;
        if (r < N_NODES) {
            st4(out + (size_t)r * 128 + cg * 8,
                make_float4(acc[i][0] + sc[cg * 8], acc[i][1] + sc[cg * 8 + 1],
                            acc[i][2] + sc[cg * 8 + 2], acc[i][3] + sc[cg * 8 + 3]));
            st4(out + (size_t)r * 128 + cg * 8 + 4,
                make_float4(acc[i][4] + sc[cg * 8 + 4], acc[i][5] + sc[cg * 8 + 5],
                            acc[i][6] + sc[cg * 8 + 6], acc[i][7] + sc[cg * 8 + 7]));
        }
    }
}

extern "C" void kernel_launch(void* const* d_in, const int* in_sizes, int n_in,
                              void* d_out, int out_size, void* d_ws, size_t ws_size,
                              hipStream_t stream) {
    const float* x     = (const float*)d_in[0];
    const int*   eidx  = (const int*)d_in[1];
    const float* ef    = (const float*)d_in[2];
    const float* eW1   = (const float*)d_in[3];
    const float* eb1   = (const float*)d_in[4];
    const float* eW2   = (const float*)d_in[5];
    const float* eb2   = (const float*)d_in[6];
    const float* egoW  = (const float*)d_in[7];
    const float* eps   = (const float*)d_in[8];
    const float* W1    = (const float*)d_in[9];
    // d_in[10] = b1: cancels in BatchNorm (uniform shift), intentionally unused
    const float* gamma = (const float*)d_in[11];
    const float* beta  = (const float*)d_in[12];
    const float* W2    = (const float*)d_in[13];
    const float* b2    = (const float*)d_in[14];
    float* out = (float*)d_out;

    char* ws = (char*)d_ws;
    float* agg    = (float*)ws;                           // N*144*4 = 28,800,000 B
    float* stats  = (float*)(ws + 28800000);              // 1 KB
    float* M      = (float*)(ws + 28801024);              // 64 KB
    float* ab     = (float*)(ws + 28866560);              // 1 KB
    int*   rowptr = (int*)(ws + 28867584);                // (N+1)*4 -> pad to 200,704 B
    int*   cursor = (int*)(ws + 29068288);                // N*4 = 200,000 B
    int*   srcs_s = (int*)(ws + 29268288);                // E*4 = 3,200,000 B  (end ~32.5 MB)
    unsigned short* esort = (unsigned short*)d_out;       // E*16 bf16 = 25.6 MB, dead before gemm1
    float* h      = out;                                  // h staged in d_out after k_agg

    hipMemsetAsync(cursor, 0, N_NODES * 4, stream);       // deg counters
    hipMemsetAsync(stats, 0, 1024, stream);
    k_prep_M<<<dim3(128), dim3(128), 0, stream>>>(egoW, W1, eps, M);
    k_hist<<<dim3((E_EDGES + 255) / 256), dim3(256), 0, stream>>>(eidx + E_EDGES, cursor);
    k_scan<<<dim3(1), dim3(1024), 0, stream>>>(cursor, rowptr);
    k_edge<<<dim3(E_EDGES / EPB), dim3(256), 0, stream>>>(ef, eidx, eW1, eb1, eW2, eb2,
                                                          cursor, srcs_s, esort);
    k_agg<<<dim3(N_NODES / 4), dim3(256), 0, stream>>>(x, rowptr, srcs_s, esort, agg);
    k_gemm1<<<dim3((N_NODES + BM - 1) / BM), dim3(256), 0, stream>>>(x, agg, M, W1, h, stats);
    k_bnparam<<<dim3(1), dim3(128), 0, stream>>>(stats, gamma, beta, ab);
    k_gemm2<<<dim3((N_NODES + BM - 1) / BM), dim3(256), 0, stream>>>(h, ab, W2, b2, out);
}

// Round 3
// 428.169 us; speedup vs baseline: 1.2467x; 1.0352x over previous
//
#include <hip/hip_runtime.h>

#define N_NODES 50000
#define E_EDGES 800000
#define D_IN    128
#define ED_IN   32
#define H_HID   16
#define D_OUT2  128
#define D_CAT   144   // D_IN + H_HID
#define EPB     64    // edges per block in edge kernel
#define BM      128   // rows per block in GEMM kernels

__device__ __forceinline__ float gelu_exact(float v) {
    return 0.5f * v * (1.0f + erff(v * 0.70710678118654752f));
}
__device__ __forceinline__ float4 ld4(const float* p) { return *reinterpret_cast<const float4*>(p); }
__device__ __forceinline__ void st4(float* p, float4 v) { *reinterpret_cast<float4*>(p) = v; }
__device__ __forceinline__ unsigned short f2bf(float f) {   // RNE bf16
    unsigned u = __float_as_uint(f);
    return (unsigned short)((u + 0x7FFFu + ((u >> 16) & 1u)) >> 16);
}
__device__ __forceinline__ float bf2f(unsigned short u) {
    return __uint_as_float(((unsigned)u) << 16);
}

// M = (1+eps) * ego_W @ W1   [128,128]
__global__ void k_prep_M(const float* __restrict__ egoW, const float* __restrict__ W1,
                         const float* __restrict__ eps, float* __restrict__ M) {
    int d = blockIdx.x;   // 0..127
    int c = threadIdx.x;  // 0..127
    float acc = 0.f;
    for (int j = 0; j < D_CAT; ++j)
        acc = fmaf(egoW[d * D_CAT + j], W1[j * D_OUT2 + c], acc);
    M[d * D_OUT2 + c] = (1.0f + eps[0]) * acc;
}

// degree histogram over dst
__global__ __launch_bounds__(256) void k_hist(const int* __restrict__ dst, int* __restrict__ deg) {
    int e = blockIdx.x * 256 + threadIdx.x;
    if (e < E_EDGES) atomicAdd(&deg[dst[e]], 1);
}

// single-block exclusive scan: cursor holds deg on entry; writes rowptr and rewrites cursor=prefix
__global__ __launch_bounds__(1024) void k_scan(int* __restrict__ cursor, int* __restrict__ rowptr) {
    const int t = threadIdx.x;
    const int CH = 50;                       // 1024*50 = 51200 >= 50000
    const int i0 = t * CH;
    int vals[CH];
    int sum = 0;
    #pragma unroll
    for (int i = 0; i < CH; ++i) {
        int idx = i0 + i;
        int v = (idx < N_NODES) ? cursor[idx] : 0;
        vals[i] = sum;
        sum += v;
    }
    __shared__ int tot[1024];
    tot[t] = sum;
    __syncthreads();
    for (int off = 1; off < 1024; off <<= 1) {
        int v = (t >= off) ? tot[t - off] : 0;
        __syncthreads();
        tot[t] += v;
        __syncthreads();
    }
    int base = tot[t] - sum;
    #pragma unroll
    for (int i = 0; i < CH; ++i) {
        int idx = i0 + i;
        if (idx < N_NODES) { int p = base + vals[i]; rowptr[idx] = p; cursor[idx] = p; }
    }
    if (t == 0) rowptr[N_NODES] = E_EDGES;
}

// Fused edge MLP + sorted placement: 1 int atomic per edge; writes src + bf16 e_emb at sorted pos
// LDS padded: efs rows 36 floats (float4-aligned, 2-way bank alias = free),
// hs/es rows 20 floats (float4-aligned writes, conflict-light reads)
__global__ __launch_bounds__(256) void k_edge(const float* __restrict__ ef,
        const int* __restrict__ eidx,
        const float* __restrict__ eW1, const float* __restrict__ eb1,
        const float* __restrict__ eW2, const float* __restrict__ eb2,
        int* __restrict__ cursor, int* __restrict__ srcs_s,
        unsigned short* __restrict__ esort) {
    __shared__ float efs[EPB][36];
    __shared__ float hs[EPB][20];
    __shared__ float es[EPB][20];
    __shared__ int   sidx[EPB];
    __shared__ int   didx[EPB];
    __shared__ int   poss[EPB];
    __shared__ float w1s[ED_IN][H_HID];
    __shared__ float w2s[H_HID][H_HID];
    __shared__ float b1s[H_HID];
    __shared__ float b2s[H_HID];

    const int t = threadIdx.x;
    const int e0 = blockIdx.x * EPB;
    const int ne = min(EPB, E_EDGES - e0);

    for (int i = t; i < ED_IN * H_HID; i += 256) w1s[i / H_HID][i % H_HID] = eW1[i];
    if (t < H_HID * H_HID) w2s[t / H_HID][t % H_HID] = eW2[t];
    if (t < H_HID) { b1s[t] = eb1[t]; b2s[t] = eb2[t]; }
    if (t < EPB)              { int le = t;       if (le < ne) sidx[le] = eidx[e0 + le]; }
    else if (t < 2 * EPB)     { int le = t - EPB; if (le < ne) didx[le] = eidx[E_EDGES + e0 + le]; }
    #pragma unroll
    for (int i = 0; i < 2; ++i) {
        int q = t + 256 * i;
        int le = q >> 3, coff = (q & 7) * 4;
        float4 v = make_float4(0.f, 0.f, 0.f, 0.f);
        if (le < ne) v = ld4(ef + (size_t)(e0 + le) * ED_IN + coff);
        st4(&efs[le][coff], v);
    }
    __syncthreads();

    const int le = t >> 2, p = t & 3;
    {   // layer 1: 4 threads/edge, 4 hidden units each; float4 weight reads
        float a0 = b1s[p * 4 + 0], a1 = b1s[p * 4 + 1], a2 = b1s[p * 4 + 2], a3 = b1s[p * 4 + 3];
        #pragma unroll
        for (int k = 0; k < ED_IN; ++k) {
            float e = efs[le][k];
            float4 w = ld4(&w1s[k][p * 4]);
            a0 = fmaf(e, w.x, a0); a1 = fmaf(e, w.y, a1);
            a2 = fmaf(e, w.z, a2); a3 = fmaf(e, w.w, a3);
        }
        if (le < ne)
            st4(&hs[le][p * 4], make_float4(gelu_exact(a0), gelu_exact(a1),
                                            gelu_exact(a2), gelu_exact(a3)));
    }
    __syncthreads();
    {   // layer 2
        float a0 = b2s[p * 4 + 0], a1 = b2s[p * 4 + 1], a2 = b2s[p * 4 + 2], a3 = b2s[p * 4 + 3];
        #pragma unroll
        for (int k = 0; k < H_HID; ++k) {
            float hv = hs[le][k];
            float4 w = ld4(&w2s[k][p * 4]);
            a0 = fmaf(hv, w.x, a0); a1 = fmaf(hv, w.y, a1);
            a2 = fmaf(hv, w.z, a2); a3 = fmaf(hv, w.w, a3);
        }
        if (le < ne) st4(&es[le][p * 4], make_float4(a0, a1, a2, a3));
    }
    __syncthreads();

    if (t < EPB && t < ne) poss[t] = atomicAdd(&cursor[didx[t]], 1);
    __syncthreads();

    if (le < ne) {   // write src + packed bf16 e_emb to sorted position (4 threads/edge, 8B each)
        int pos = poss[le];
        if (p == 0) srcs_s[pos] = sidx[le];
        ushort4 w;
        w.x = f2bf(es[le][p * 4 + 0]);
        w.y = f2bf(es[le][p * 4 + 1]);
        w.z = f2bf(es[le][p * 4 + 2]);
        w.w = f2bf(es[le][p * 4 + 3]);
        *reinterpret_cast<ushort4*>(esort + (size_t)pos * 16 + p * 4) = w;
    }
}

// CSR aggregation: one wave per node; 2 edges/iteration (32 lanes x float4 each); no atomics
__global__ __launch_bounds__(256) void k_agg(const float* __restrict__ x,
        const int* __restrict__ rowptr, const int* __restrict__ srcs_s,
        const unsigned short* __restrict__ esort, float* __restrict__ agg) {
    const int wave = threadIdx.x >> 6, lane = threadIdx.x & 63;
    const int half = lane >> 5, hl = lane & 31;
    const int n = blockIdx.x * 4 + wave;           // grid 12500 -> exactly 50000
    const int beg = rowptr[n], end = rowptr[n + 1];
    float4 a = make_float4(0.f, 0.f, 0.f, 0.f);
    float ae = 0.f;
    for (int base = beg; base < end; base += 64) {
        const int m = min(64, end - base);
        int sv = (base + lane < end) ? srcs_s[base + lane] : 0;
        const int npair = (m + 1) >> 1;
        #pragma unroll 2
        for (int j = 0; j < npair; ++j) {
            const int eo = 2 * j + half;           // edge offset within chunk for this half
            const int s = __shfl(sv, eo);
            if (eo < m) {
                float4 v = ld4(x + (size_t)s * D_IN + hl * 4);
                a.x += v.x; a.y += v.y; a.z += v.z; a.w += v.w;
                if (hl < H_HID) ae += bf2f(esort[(size_t)(base + eo) * 16 + hl]);
            }
        }
    }
    // combine the two 32-lane halves (same channel layout in both)
    a.x += __shfl_xor(a.x, 32); a.y += __shfl_xor(a.y, 32);
    a.z += __shfl_xor(a.z, 32); a.w += __shfl_xor(a.w, 32);
    ae  += __shfl_xor(ae, 32);
    if (half == 0) {
        float* ar = agg + (size_t)n * D_CAT;
        st4(ar + hl * 4, a);
        if (hl < H_HID) ar[D_IN + hl] = ae;
    }
}

// h = x @ M + agg @ W1   (b1 cancels in BN); also accumulate col sums / sumsq
__global__ __launch_bounds__(256) void k_gemm1(const float* __restrict__ x,
        const float* __restrict__ agg, const float* __restrict__ M,
        const float* __restrict__ W1, float* __restrict__ h, float* __restrict__ stats) {
    __shared__ float As[128][20];
    __shared__ float Bs[16][132];
    __shared__ float red0[128];
    __shared__ float red1[128];
    const int t = threadIdx.x;
    const int row0 = blockIdx.x * BM;
    const int rg = t >> 4, cg = t & 15;
    float acc[8][8];
    #pragma unroll
    for (int i = 0; i < 8; ++i)
        #pragma unroll
        for (int j = 0; j < 8; ++j) acc[i][j] = 0.f;

    #pragma unroll 1
    for (int ch = 0; ch < 17; ++ch) {
        const float* Ap; const float* Bp; int lda, k0;
        if (ch < 8) { Ap = x;   lda = D_IN;  k0 = ch * 16;       Bp = M  + k0 * 128; }
        else        { Ap = agg; lda = D_CAT; k0 = (ch - 8) * 16; Bp = W1 + k0 * 128; }
        #pragma unroll
        for (int i = 0; i < 2; ++i) {
            int q = t + 256 * i;
            int row = q >> 2, coff = (q & 3) * 4;
            int r = row0 + row;
            float4 v = make_float4(0.f, 0.f, 0.f, 0.f);
            if (r < N_NODES) v = ld4(Ap + (size_t)r * lda + k0 + coff);
            st4(&As[row][coff], v);
        }
        #pragma unroll
        for (int i = 0; i < 2; ++i) {
            int q = t + 256 * i;
            int row = q >> 5, coff = (q & 31) * 4;
            st4(&Bs[row][coff], ld4(Bp + row * 128 + coff));
        }
        __syncthreads();
        #pragma unroll
        for (int kk = 0; kk < 16; ++kk) {
            float a[8];
            #pragma unroll
            for (int i = 0; i < 8; ++i) a[i] = As[rg * 8 + i][kk];
            float4 b0 = ld4(&Bs[kk][cg * 8]);
            float4 b1v = ld4(&Bs[kk][cg * 8 + 4]);
            float b[8] = {b0.x, b0.y, b0.z, b0.w, b1v.x, b1v.y, b1v.z, b1v.w};
            #pragma unroll
            for (int i = 0; i < 8; ++i)
                #pragma unroll
                for (int j = 0; j < 8; ++j)
                    acc[i][j] = fmaf(a[i], b[j], acc[i][j]);
        }
        __syncthreads();
    }

    if (t < 128) { red0[t] = 0.f; red1[t] = 0.f; }
    __syncthreads();
    float s0[8], s1[8];
    #pragma unroll
    for (int j = 0; j < 8; ++j) { s0[j] = 0.f; s1[j] = 0.f; }
    #pragma unroll
    for (int i = 0; i < 8; ++i) {
        int r = row0 + rg * 8 + i;
        if (r < N_NODES) {
            st4(h + (size_t)r * 128 + cg * 8,     make_float4(acc[i][0], acc[i][1], acc[i][2], acc[i][3]));
            st4(h + (size_t)r * 128 + cg * 8 + 4, make_float4(acc[i][4], acc[i][5], acc[i][6], acc[i][7]));
            #pragma unroll
            for (int j = 0; j < 8; ++j) { float v = acc[i][j]; s0[j] += v; s1[j] += v * v; }
        }
    }
    #pragma unroll
    for (int j = 0; j < 8; ++j) {
        atomicAdd(&red0[cg * 8 + j], s0[j]);
        atomicAdd(&red1[cg * 8 + j], s1[j]);
    }
    __syncthreads();
    if (t < 128) {
        unsafeAtomicAdd(stats + t,       red0[t]);
        unsafeAtomicAdd(stats + 128 + t, red1[t]);
    }
}

// BN affine params: a = gamma*rsqrt(var+eps), b = beta - mu*a
__global__ void k_bnparam(const float* __restrict__ stats, const float* __restrict__ gamma,
                          const float* __restrict__ beta, float* __restrict__ ab) {
    int c = threadIdx.x;
    float mu  = stats[c] * (1.0f / N_NODES);
    float var = stats[128 + c] * (1.0f / N_NODES) - mu * mu;
    float a = gamma[c] * rsqrtf(var + 1e-5f);
    ab[c] = a;
    ab[128 + c] = beta[c] - mu * a;
}

// out = GELU(a*h+b) @ W2 + b2 ; h lives in d_out (in-place safe: block reads only its own rows)
__global__ __launch_bounds__(256) void k_gemm2(const float* __restrict__ h,
        const float* __restrict__ ab, const float* __restrict__ W2,
        const float* __restrict__ b2, float* __restrict__ out) {
    __shared__ float gs[128][128];
    __shared__ float Bs[16][132];
    __shared__ float sa[128], sb[128], sc[128];
    const int t = threadIdx.x;
    const int row0 = blockIdx.x * BM;
    if (t < 128) { sa[t] = ab[t]; sb[t] = ab[128 + t]; sc[t] = b2[t]; }
    __syncthreads();
    #pragma unroll
    for (int i = 0; i < 16; ++i) {
        int q = t + 256 * i;
        int row = q >> 5, coff = (q & 31) * 4;
        int r = row0 + row;
        float4 v = make_float4(0.f, 0.f, 0.f, 0.f);
        if (r < N_NODES) v = ld4(h + (size_t)r * 128 + coff);
        v.x = gelu_exact(fmaf(sa[coff],     v.x, sb[coff]));
        v.y = gelu_exact(fmaf(sa[coff + 1], v.y, sb[coff + 1]));
        v.z = gelu_exact(fmaf(sa[coff + 2], v.z, sb[coff + 2]));
        v.w = gelu_exact(fmaf(sa[coff + 3], v.w, sb[coff + 3]));
        st4(&gs[row][coff], v);
    }
    __syncthreads();
    const int rg = t >> 4, cg = t & 15;
    float acc[8][8];
    #pragma unroll
    for (int i = 0; i < 8; ++i)
        #pragma unroll
        for (int j = 0; j < 8; ++j) acc[i][j] = 0.f;
    #pragma unroll 1
    for (int ch = 0; ch < 8; ++ch) {
        #pragma unroll
        for (int i = 0; i < 2; ++i) {
            int q = t + 256 * i;
            int row = q >> 5, coff = (q & 31) * 4;
            st4(&Bs[row][coff], ld4(W2 + (ch * 16 + row) * 128 + coff));
        }
        __syncthreads();
        #pragma unroll
        for (int kk = 0; kk < 16; ++kk) {
            int k = ch * 16 + kk;
            float a[8];
            #pragma unroll
            for (int i = 0; i < 8; ++i) a[i] = gs[rg * 8 + i][k];
            float4 b0 = ld4(&Bs[kk][cg * 8]);
            float4 b1v = ld4(&Bs[kk][cg * 8 + 4]);
            float b[8] = {b0.x, b0.y, b0.z, b0.w, b1v.x, b1v.y, b1v.z, b1v.w};
            #pragma unroll
            for (int i = 0; i < 8; ++i)
                #pragma unroll
                for (int j = 0; j < 8; ++j)
                    acc[i][j] = fmaf(a[i], b[j], acc[i][j]);
        }
        __syncthreads();
    }
    #pragma unroll
    for (int i = 0; i < 8; ++i) {
        int r = row0 + rg * 8 + i;
        if (r < N_NODES) {
            st4(out + (size_t)r * 128 + cg * 8,
                make_float4(acc[i][0] + sc[cg * 8], acc[i][1] + sc[cg * 8 + 1],
                            acc[i][2] + sc[cg * 8 + 2], acc[i][3] + sc[cg * 8 + 3]));
            st4(out + (size_t)r * 128 + cg * 8 + 4,
                make_float4(acc[i][4] + sc[cg * 8 + 4], acc[i][5] + sc[cg * 8 + 5],
                            acc[i][6] + sc[cg * 8 + 6], acc[i][7] + sc[cg * 8 + 7]));
        }
    }
}

extern "C" void kernel_launch(void* const* d_in, const int* in_sizes, int n_in,
                              void* d_out, int out_size, void* d_ws, size_t ws_size,
                              hipStream_t stream) {
    const float* x     = (const float*)d_in[0];
    const int*   eidx  = (const int*)d_in[1];
    const float* ef    = (const float*)d_in[2];
    const float* eW1   = (const float*)d_in[3];
    const float* eb1   = (const float*)d_in[4];
    const float* eW2   = (const float*)d_in[5];
    const float* eb2   = (const float*)d_in[6];
    const float* egoW  = (const float*)d_in[7];
    const float* eps   = (const float*)d_in[8];
    const float* W1    = (const float*)d_in[9];
    // d_in[10] = b1: cancels in BatchNorm (uniform shift), intentionally unused
    const float* gamma = (const float*)d_in[11];
    const float* beta  = (const float*)d_in[12];
    const float* W2    = (const float*)d_in[13];
    const float* b2    = (const float*)d_in[14];
    float* out = (float*)d_out;

    char* ws = (char*)d_ws;
    float* agg    = (float*)ws;                           // N*144*4 = 28,800,000 B
    float* stats  = (float*)(ws + 28800000);              // 1 KB
    float* M      = (float*)(ws + 28801024);              // 64 KB
    float* ab     = (float*)(ws + 28866560);              // 1 KB
    int*   rowptr = (int*)(ws + 28867584);                // (N+1)*4 -> pad to 200,704 B
    int*   cursor = (int*)(ws + 29068288);                // N*4 = 200,000 B
    int*   srcs_s = (int*)(ws + 29268288);                // E*4 = 3,200,000 B  (end ~32.5 MB)
    unsigned short* esort = (unsigned short*)d_out;       // E*16 bf16 = 25.6 MB, dead before gemm1
    float* h      = out;                                  // h staged in d_out after k_agg

    hipMemsetAsync(cursor, 0, N_NODES * 4, stream);       // deg counters
    hipMemsetAsync(stats, 0, 1024, stream);
    k_prep_M<<<dim3(128), dim3(128), 0, stream>>>(egoW, W1, eps, M);
    k_hist<<<dim3((E_EDGES + 255) / 256), dim3(256), 0, stream>>>(eidx + E_EDGES, cursor);
    k_scan<<<dim3(1), dim3(1024), 0, stream>>>(cursor, rowptr);
    k_edge<<<dim3(E_EDGES / EPB), dim3(256), 0, stream>>>(ef, eidx, eW1, eb1, eW2, eb2,
                                                          cursor, srcs_s, esort);
    k_agg<<<dim3(N_NODES / 4), dim3(256), 0, stream>>>(x, rowptr, srcs_s, esort, agg);
    k_gemm1<<<dim3((N_NODES + BM - 1) / BM), dim3(256), 0, stream>>>(x, agg, M, W1, h, stats);
    k_bnparam<<<dim3(1), dim3(128), 0, stream>>>(stats, gamma, beta, ab);
    k_gemm2<<<dim3((N_NODES + BM - 1) / BM), dim3(256), 0, stream>>>(h, ab, W2, b2, out);
}

// Round 4
// 337.087 us; speedup vs baseline: 1.5836x; 1.2702x over previous
//
#include <hip/hip_runtime.h>

#define N_NODES 50000
#define E_EDGES 800000
#define D_IN    128
#define ED_IN   32
#define H_HID   16
#define D_OUT2  128
#define D_CAT   144   // D_IN + H_HID
#define EPB     64    // edges per block in edge kernel (E_EDGES % EPB == 0 -> no tails)
#define BM      128   // rows per block in GEMM kernels

__device__ __forceinline__ float gelu_exact(float v) {
    return 0.5f * v * (1.0f + erff(v * 0.70710678118654752f));
}
__device__ __forceinline__ float4 ld4(const float* p) { return *reinterpret_cast<const float4*>(p); }
__device__ __forceinline__ void st4(float* p, float4 v) { *reinterpret_cast<float4*>(p) = v; }
__device__ __forceinline__ unsigned short f2bf(float f) {   // RNE bf16
    unsigned u = __float_as_uint(f);
    return (unsigned short)((u + 0x7FFFu + ((u >> 16) & 1u)) >> 16);
}
__device__ __forceinline__ float bf2f(unsigned short u) {
    return __uint_as_float(((unsigned)u) << 16);
}

// M = (1+eps) * ego_W @ W1   [128,128]
__global__ void k_prep_M(const float* __restrict__ egoW, const float* __restrict__ W1,
                         const float* __restrict__ eps, float* __restrict__ M) {
    int d = blockIdx.x;   // 0..127
    int c = threadIdx.x;  // 0..127
    float acc = 0.f;
    for (int j = 0; j < D_CAT; ++j)
        acc = fmaf(egoW[d * D_CAT + j], W1[j * D_OUT2 + c], acc);
    M[d * D_OUT2 + c] = (1.0f + eps[0]) * acc;
}

// degree histogram over dst
__global__ __launch_bounds__(256) void k_hist(const int* __restrict__ dst, int* __restrict__ deg) {
    int e = blockIdx.x * 256 + threadIdx.x;
    if (e < E_EDGES) atomicAdd(&deg[dst[e]], 1);
}

// single-block exclusive scan: cursor holds deg on entry; writes rowptr and rewrites cursor=prefix
__global__ __launch_bounds__(1024) void k_scan(int* __restrict__ cursor, int* __restrict__ rowptr) {
    const int t = threadIdx.x;
    const int CH = 52;                       // 1024*52 = 53248 >= 50000; 52 % 4 == 0 for int4
    const int i0 = t * CH;
    int vals[CH];
    int sum = 0;
    if (i0 + CH <= N_NODES) {
        #pragma unroll
        for (int q = 0; q < CH / 4; ++q) {
            int4 v = *reinterpret_cast<const int4*>(cursor + i0 + q * 4);
            vals[q * 4 + 0] = sum; sum += v.x;
            vals[q * 4 + 1] = sum; sum += v.y;
            vals[q * 4 + 2] = sum; sum += v.z;
            vals[q * 4 + 3] = sum; sum += v.w;
        }
    } else {
        #pragma unroll
        for (int i = 0; i < CH; ++i) {
            int idx = i0 + i;
            int v = (idx < N_NODES) ? cursor[idx] : 0;
            vals[i] = sum; sum += v;
        }
    }
    __shared__ int tot[1024];
    tot[t] = sum;
    __syncthreads();
    for (int off = 1; off < 1024; off <<= 1) {
        int v = (t >= off) ? tot[t - off] : 0;
        __syncthreads();
        tot[t] += v;
        __syncthreads();
    }
    const int base = tot[t] - sum;
    if (i0 + CH <= N_NODES) {
        #pragma unroll
        for (int q = 0; q < CH / 4; ++q) {
            int4 pv = make_int4(base + vals[q * 4 + 0], base + vals[q * 4 + 1],
                                base + vals[q * 4 + 2], base + vals[q * 4 + 3]);
            *reinterpret_cast<int4*>(rowptr + i0 + q * 4) = pv;
            *reinterpret_cast<int4*>(cursor + i0 + q * 4) = pv;
        }
    } else {
        #pragma unroll
        for (int i = 0; i < CH; ++i) {
            int idx = i0 + i;
            if (idx < N_NODES) { int p = base + vals[i]; rowptr[idx] = p; cursor[idx] = p; }
        }
    }
    if (t == 0) rowptr[N_NODES] = E_EDGES;
}

// Fused edge MLP + sorted placement: 1 int atomic per edge; writes src + bf16 e_emb at sorted pos
// Round-2 code shape (scalar weight reads -> VGPR ~32, occupancy ~80%), LDS padded:
//   efs stride 36 (2-way alias = free), hs/es stride 17 (coprime 32 = conflict-free)
__global__ __launch_bounds__(256) void k_edge(const float* __restrict__ ef,
        const int* __restrict__ eidx,
        const float* __restrict__ eW1, const float* __restrict__ eb1,
        const float* __restrict__ eW2, const float* __restrict__ eb2,
        int* __restrict__ cursor, int* __restrict__ srcs_s,
        unsigned short* __restrict__ esort) {
    __shared__ float efs[EPB][36];
    __shared__ float hs[EPB][17];
    __shared__ float es[EPB][17];
    __shared__ int   sidx[EPB];
    __shared__ int   didx[EPB];
    __shared__ int   poss[EPB];
    __shared__ float w1s[ED_IN][H_HID];
    __shared__ float w2s[H_HID][H_HID];
    __shared__ float b1s[H_HID];
    __shared__ float b2s[H_HID];

    const int t = threadIdx.x;
    const int e0 = blockIdx.x * EPB;     // always a full block of 64 edges

    for (int i = t; i < ED_IN * H_HID; i += 256) w1s[i / H_HID][i % H_HID] = eW1[i];
    w2s[t / H_HID][t % H_HID] = eW2[t];  // 256 entries, 256 threads
    if (t < H_HID) { b1s[t] = eb1[t]; b2s[t] = eb2[t]; }
    if (t < EPB)              sidx[t] = eidx[e0 + t];
    else if (t < 2 * EPB)     didx[t - EPB] = eidx[E_EDGES + e0 + (t - EPB)];
    #pragma unroll
    for (int i = 0; i < 2; ++i) {
        int q = t + 256 * i;
        int le = q >> 3, coff = (q & 7) * 4;
        st4(&efs[le][coff], ld4(ef + (size_t)(e0 + le) * ED_IN + coff));
    }
    __syncthreads();

    const int le = t >> 2, p = t & 3;
    {   // layer 1: 4 threads/edge, 4 hidden units each (scalar weight reads broadcast free)
        #pragma unroll
        for (int jj = 0; jj < 4; ++jj) {
            int j = p * 4 + jj;
            float acc = b1s[j];
            #pragma unroll
            for (int k = 0; k < ED_IN; ++k) acc = fmaf(efs[le][k], w1s[k][j], acc);
            hs[le][j] = gelu_exact(acc);
        }
    }
    __syncthreads();
    {   // layer 2
        #pragma unroll
        for (int cc = 0; cc < 4; ++cc) {
            int c = p * 4 + cc;
            float acc = b2s[c];
            #pragma unroll
            for (int k = 0; k < H_HID; ++k) acc = fmaf(hs[le][k], w2s[k][c], acc);
            es[le][c] = acc;
        }
    }
    __syncthreads();

    if (t < EPB) poss[t] = atomicAdd(&cursor[didx[t]], 1);
    __syncthreads();

    {   // write src + packed bf16 e_emb to sorted position (4 threads/edge, 8B each)
        int pos = poss[le];
        if (p == 0) srcs_s[pos] = sidx[le];
        ushort4 w;
        w.x = f2bf(es[le][p * 4 + 0]);
        w.y = f2bf(es[le][p * 4 + 1]);
        w.z = f2bf(es[le][p * 4 + 2]);
        w.w = f2bf(es[le][p * 4 + 3]);
        *reinterpret_cast<ushort4*>(esort + (size_t)pos * 16 + p * 4) = w;
    }
}

// CSR aggregation: one wave per node; 2 edges/iteration (32 lanes x float4 each); no atomics
__global__ __launch_bounds__(256) void k_agg(const float* __restrict__ x,
        const int* __restrict__ rowptr, const int* __restrict__ srcs_s,
        const unsigned short* __restrict__ esort, float* __restrict__ agg) {
    const int wave = threadIdx.x >> 6, lane = threadIdx.x & 63;
    const int half = lane >> 5, hl = lane & 31;
    const int n = blockIdx.x * 4 + wave;           // grid 12500 -> exactly 50000
    const int beg = rowptr[n], end = rowptr[n + 1];
    const unsigned short* ep = esort + hl;         // lane-fixed esort column
    float4 a = make_float4(0.f, 0.f, 0.f, 0.f);
    float ae = 0.f;
    for (int base = beg; base < end; base += 64) {
        const int m = min(64, end - base);
        int sv = (base + lane < end) ? srcs_s[base + lane] : 0;
        const int npair = (m + 1) >> 1;
        #pragma unroll 4
        for (int j = 0; j < npair; ++j) {
            const int eo = 2 * j + half;           // edge offset within chunk for this half
            const int s = __shfl(sv, eo);
            if (eo < m) {
                float4 v = ld4(x + (size_t)s * D_IN + hl * 4);
                a.x += v.x; a.y += v.y; a.z += v.z; a.w += v.w;
                if (hl < H_HID) ae += bf2f(ep[(size_t)(base + eo) * 16]);
            }
        }
    }
    // combine the two 32-lane halves (same channel layout in both)
    a.x += __shfl_xor(a.x, 32); a.y += __shfl_xor(a.y, 32);
    a.z += __shfl_xor(a.z, 32); a.w += __shfl_xor(a.w, 32);
    ae  += __shfl_xor(ae, 32);
    if (half == 0) {
        float* ar = agg + (size_t)n * D_CAT;
        st4(ar + hl * 4, a);
        if (hl < H_HID) ar[D_IN + hl] = ae;
    }
}

// h = x @ M + agg @ W1   (b1 cancels in BN); also accumulate col sums / sumsq
__global__ __launch_bounds__(256) void k_gemm1(const float* __restrict__ x,
        const float* __restrict__ agg, const float* __restrict__ M,
        const float* __restrict__ W1, float* __restrict__ h, float* __restrict__ stats) {
    __shared__ float As[128][20];
    __shared__ float Bs[16][132];
    __shared__ float red0[128];
    __shared__ float red1[128];
    const int t = threadIdx.x;
    const int row0 = blockIdx.x * BM;
    const int rg = t >> 4, cg = t & 15;
    float acc[8][8];
    #pragma unroll
    for (int i = 0; i < 8; ++i)
        #pragma unroll
        for (int j = 0; j < 8; ++j) acc[i][j] = 0.f;

    #pragma unroll 1
    for (int ch = 0; ch < 17; ++ch) {
        const float* Ap; const float* Bp; int lda, k0;
        if (ch < 8) { Ap = x;   lda = D_IN;  k0 = ch * 16;       Bp = M  + k0 * 128; }
        else        { Ap = agg; lda = D_CAT; k0 = (ch - 8) * 16; Bp = W1 + k0 * 128; }
        #pragma unroll
        for (int i = 0; i < 2; ++i) {
            int q = t + 256 * i;
            int row = q >> 2, coff = (q & 3) * 4;
            int r = row0 + row;
            float4 v = make_float4(0.f, 0.f, 0.f, 0.f);
            if (r < N_NODES) v = ld4(Ap + (size_t)r * lda + k0 + coff);
            st4(&As[row][coff], v);
        }
        #pragma unroll
        for (int i = 0; i < 2; ++i) {
            int q = t + 256 * i;
            int row = q >> 5, coff = (q & 31) * 4;
            st4(&Bs[row][coff], ld4(Bp + row * 128 + coff));
        }
        __syncthreads();
        #pragma unroll
        for (int kk = 0; kk < 16; ++kk) {
            float a[8];
            #pragma unroll
            for (int i = 0; i < 8; ++i) a[i] = As[rg * 8 + i][kk];
            float4 b0 = ld4(&Bs[kk][cg * 8]);
            float4 b1v = ld4(&Bs[kk][cg * 8 + 4]);
            float b[8] = {b0.x, b0.y, b0.z, b0.w, b1v.x, b1v.y, b1v.z, b1v.w};
            #pragma unroll
            for (int i = 0; i < 8; ++i)
                #pragma unroll
                for (int j = 0; j < 8; ++j)
                    acc[i][j] = fmaf(a[i], b[j], acc[i][j]);
        }
        __syncthreads();
    }

    if (t < 128) { red0[t] = 0.f; red1[t] = 0.f; }
    __syncthreads();
    float s0[8], s1[8];
    #pragma unroll
    for (int j = 0; j < 8; ++j) { s0[j] = 0.f; s1[j] = 0.f; }
    #pragma unroll
    for (int i = 0; i < 8; ++i) {
        int r = row0 + rg * 8 + i;
        if (r < N_NODES) {
            st4(h + (size_t)r * 128 + cg * 8,     make_float4(acc[i][0], acc[i][1], acc[i][2], acc[i][3]));
            st4(h + (size_t)r * 128 + cg * 8 + 4, make_float4(acc[i][4], acc[i][5], acc[i][6], acc[i][7]));
            #pragma unroll
            for (int j = 0; j < 8; ++j) { float v = acc[i][j]; s0[j] += v; s1[j] += v * v; }
        }
    }
    #pragma unroll
    for (int j = 0; j < 8; ++j) {
        atomicAdd(&red0[cg * 8 + j], s0[j]);
        atomicAdd(&red1[cg * 8 + j], s1[j]);
    }
    __syncthreads();
    if (t < 128) {
        unsafeAtomicAdd(stats + t,       red0[t]);
        unsafeAtomicAdd(stats + 128 + t, red1[t]);
    }
}

// BN affine params: a = gamma*rsqrt(var+eps), b = beta - mu*a
__global__ void k_bnparam(const float* __restrict__ stats, const float* __restrict__ gamma,
                          const float* __restrict__ beta, float* __restrict__ ab) {
    int c = threadIdx.x;
    float mu  = stats[c] * (1.0f / N_NODES);
    float var = stats[128 + c] * (1.0f / N_NODES) - mu * mu;
    float a = gamma[c] * rsqrtf(var + 1e-5f);
    ab[c] = a;
    ab[128 + c] = beta[c] - mu * a;
}

// out = GELU(a*h+b) @ W2 + b2 ; h lives in d_out (in-place safe: block reads only its own rows)
__global__ __launch_bounds__(256) void k_gemm2(const float* __restrict__ h,
        const float* __restrict__ ab, const float* __restrict__ W2,
        const float* __restrict__ b2, float* __restrict__ out) {
    __shared__ float gs[128][128];
    __shared__ float Bs[16][132];
    __shared__ float sa[128], sb[128], sc[128];
    const int t = threadIdx.x;
    const int row0 = blockIdx.x * BM;
    if (t < 128) { sa[t] = ab[t]; sb[t] = ab[128 + t]; sc[t] = b2[t]; }
    __syncthreads();
    #pragma unroll
    for (int i = 0; i < 16; ++i) {
        int q = t + 256 * i;
        int row = q >> 5, coff = (q & 31) * 4;
        int r = row0 + row;
        float4 v = make_float4(0.f, 0.f, 0.f, 0.f);
        if (r < N_NODES) v = ld4(h + (size_t)r * 128 + coff);
        v.x = gelu_exact(fmaf(sa[coff],     v.x, sb[coff]));
        v.y = gelu_exact(fmaf(sa[coff + 1], v.y, sb[coff + 1]));
        v.z = gelu_exact(fmaf(sa[coff + 2], v.z, sb[coff + 2]));
        v.w = gelu_exact(fmaf(sa[coff + 3], v.w, sb[coff + 3]));
        st4(&gs[row][coff], v);
    }
    __syncthreads();
    const int rg = t >> 4, cg = t & 15;
    float acc[8][8];
    #pragma unroll
    for (int i = 0; i < 8; ++i)
        #pragma unroll
        for (int j = 0; j < 8; ++j) acc[i][j] = 0.f;
    #pragma unroll 1
    for (int ch = 0; ch < 8; ++ch) {
        #pragma unroll
        for (int i = 0; i < 2; ++i) {
            int q = t + 256 * i;
            int row = q >> 5, coff = (q & 31) * 4;
            st4(&Bs[row][coff], ld4(W2 + (ch * 16 + row) * 128 + coff));
        }
        __syncthreads();
        #pragma unroll
        for (int kk = 0; kk < 16; ++kk) {
            int k = ch * 16 + kk;
            float a[8];
            #pragma unroll
            for (int i = 0; i < 8; ++i) a[i] = gs[rg * 8 + i][k];
            float4 b0 = ld4(&Bs[kk][cg * 8]);
            float4 b1v = ld4(&Bs[kk][cg * 8 + 4]);
            float b[8] = {b0.x, b0.y, b0.z, b0.w, b1v.x, b1v.y, b1v.z, b1v.w};
            #pragma unroll
            for (int i = 0; i < 8; ++i)
                #pragma unroll
                for (int j = 0; j < 8; ++j)
                    acc[i][j] = fmaf(a[i], b[j], acc[i][j]);
        }
        __syncthreads();
    }
    #pragma unroll
    for (int i = 0; i < 8; ++i) {
        int r = row0 + rg * 8 + i;
        if (r < N_NODES) {
            st4(out + (size_t)r * 128 + cg * 8,
                make_float4(acc[i][0] + sc[cg * 8], acc[i][1] + sc[cg * 8 + 1],
                            acc[i][2] + sc[cg * 8 + 2], acc[i][3] + sc[cg * 8 + 3]));
            st4(out + (size_t)r * 128 + cg * 8 + 4,
                make_float4(acc[i][4] + sc[cg * 8 + 4], acc[i][5] + sc[cg * 8 + 5],
                            acc[i][6] + sc[cg * 8 + 6], acc[i][7] + sc[cg * 8 + 7]));
        }
    }
}

extern "C" void kernel_launch(void* const* d_in, const int* in_sizes, int n_in,
                              void* d_out, int out_size, void* d_ws, size_t ws_size,
                              hipStream_t stream) {
    const float* x     = (const float*)d_in[0];
    const int*   eidx  = (const int*)d_in[1];
    const float* ef    = (const float*)d_in[2];
    const float* eW1   = (const float*)d_in[3];
    const float* eb1   = (const float*)d_in[4];
    const float* eW2   = (const float*)d_in[5];
    const float* eb2   = (const float*)d_in[6];
    const float* egoW  = (const float*)d_in[7];
    const float* eps   = (const float*)d_in[8];
    const float* W1    = (const float*)d_in[9];
    // d_in[10] = b1: cancels in BatchNorm (uniform shift), intentionally unused
    const float* gamma = (const float*)d_in[11];
    const float* beta  = (const float*)d_in[12];
    const float* W2    = (const float*)d_in[13];
    const float* b2    = (const float*)d_in[14];
    float* out = (float*)d_out;

    char* ws = (char*)d_ws;
    float* agg    = (float*)ws;                           // N*144*4 = 28,800,000 B
    float* stats  = (float*)(ws + 28800000);              // 1 KB
    float* M      = (float*)(ws + 28801024);              // 64 KB
    float* ab     = (float*)(ws + 28866560);              // 1 KB
    int*   rowptr = (int*)(ws + 28867584);                // (N+1)*4 -> pad to 200,704 B
    int*   cursor = (int*)(ws + 29068288);                // N*4 = 200,000 B
    int*   srcs_s = (int*)(ws + 29268288);                // E*4 = 3,200,000 B  (end ~32.5 MB)
    unsigned short* esort = (unsigned short*)d_out;       // E*16 bf16 = 25.6 MB, dead before gemm1
    float* h      = out;                                  // h staged in d_out after k_agg

    hipMemsetAsync(cursor, 0, N_NODES * 4, stream);       // deg counters
    hipMemsetAsync(stats, 0, 1024, stream);
    k_prep_M<<<dim3(128), dim3(128), 0, stream>>>(egoW, W1, eps, M);
    k_hist<<<dim3((E_EDGES + 255) / 256), dim3(256), 0, stream>>>(eidx + E_EDGES, cursor);
    k_scan<<<dim3(1), dim3(1024), 0, stream>>>(cursor, rowptr);
    k_edge<<<dim3(E_EDGES / EPB), dim3(256), 0, stream>>>(ef, eidx, eW1, eb1, eW2, eb2,
                                                          cursor, srcs_s, esort);
    k_agg<<<dim3(N_NODES / 4), dim3(256), 0, stream>>>(x, rowptr, srcs_s, esort, agg);
    k_gemm1<<<dim3((N_NODES + BM - 1) / BM), dim3(256), 0, stream>>>(x, agg, M, W1, h, stats);
    k_bnparam<<<dim3(1), dim3(128), 0, stream>>>(stats, gamma, beta, ab);
    k_gemm2<<<dim3((N_NODES + BM - 1) / BM), dim3(256), 0, stream>>>(h, ab, W2, b2, out);
}

// Round 5
// 316.622 us; speedup vs baseline: 1.6859x; 1.0646x over previous
//
#include <hip/hip_runtime.h>

#define N_NODES 50000
#define E_EDGES 800000
#define D_IN    128
#define ED_IN   32
#define H_HID   16
#define D_OUT2  128
#define D_CAT   144   // D_IN + H_HID
#define EPB     64    // edges per block in edge kernel (E_EDGES % EPB == 0 -> no tails)
#define BM      128   // rows per block in GEMM kernels

__device__ __forceinline__ float gelu_exact(float v) {
    return 0.5f * v * (1.0f + erff(v * 0.70710678118654752f));
}
__device__ __forceinline__ float4 ld4(const float* p) { return *reinterpret_cast<const float4*>(p); }
__device__ __forceinline__ void st4(float* p, float4 v) { *reinterpret_cast<float4*>(p) = v; }
__device__ __forceinline__ unsigned short f2bf(float f) {   // RNE bf16
    unsigned u = __float_as_uint(f);
    return (unsigned short)((u + 0x7FFFu + ((u >> 16) & 1u)) >> 16);
}
__device__ __forceinline__ float bf2f(unsigned short u) {
    return __uint_as_float(((unsigned)u) << 16);
}
__device__ __forceinline__ float bflo(unsigned u) { return __uint_as_float(u << 16); }
__device__ __forceinline__ float bfhi(unsigned u) { return __uint_as_float(u & 0xffff0000u); }
__device__ __forceinline__ unsigned packbf(float lo, float hi) {
    return (unsigned)f2bf(lo) | ((unsigned)f2bf(hi) << 16);
}

// M = (1+eps) * ego_W @ W1   [128,128]
__global__ void k_prep_M(const float* __restrict__ egoW, const float* __restrict__ W1,
                         const float* __restrict__ eps, float* __restrict__ M) {
    int d = blockIdx.x;   // 0..127
    int c = threadIdx.x;  // 0..127
    float acc = 0.f;
    for (int j = 0; j < D_CAT; ++j)
        acc = fmaf(egoW[d * D_CAT + j], W1[j * D_OUT2 + c], acc);
    M[d * D_OUT2 + c] = (1.0f + eps[0]) * acc;
}

// x [N,128] f32 -> xb bf16 (packed pairs). 6.4M floats = 800000 uint4 outputs.
__global__ __launch_bounds__(256) void k_cast(const float* __restrict__ x, uint4* __restrict__ xb) {
    int i = blockIdx.x * 256 + threadIdx.x;     // grid 3125*256 == 800000 exactly
    float4 f0 = ld4(x + (size_t)i * 8);
    float4 f1 = ld4(x + (size_t)i * 8 + 4);
    uint4 o;
    o.x = packbf(f0.x, f0.y); o.y = packbf(f0.z, f0.w);
    o.z = packbf(f1.x, f1.y); o.w = packbf(f1.z, f1.w);
    xb[i] = o;
}

// degree histogram over dst
__global__ __launch_bounds__(256) void k_hist(const int* __restrict__ dst, int* __restrict__ deg) {
    int e = blockIdx.x * 256 + threadIdx.x;
    if (e < E_EDGES) atomicAdd(&deg[dst[e]], 1);
}

// single-block exclusive scan: cursor holds deg on entry; writes rowptr and rewrites cursor=prefix
__global__ __launch_bounds__(1024) void k_scan(int* __restrict__ cursor, int* __restrict__ rowptr) {
    const int t = threadIdx.x;
    const int CH = 52;                       // 1024*52 = 53248 >= 50000; 52 % 4 == 0 for int4
    const int i0 = t * CH;
    int vals[CH];
    int sum = 0;
    if (i0 + CH <= N_NODES) {
        #pragma unroll
        for (int q = 0; q < CH / 4; ++q) {
            int4 v = *reinterpret_cast<const int4*>(cursor + i0 + q * 4);
            vals[q * 4 + 0] = sum; sum += v.x;
            vals[q * 4 + 1] = sum; sum += v.y;
            vals[q * 4 + 2] = sum; sum += v.z;
            vals[q * 4 + 3] = sum; sum += v.w;
        }
    } else {
        #pragma unroll
        for (int i = 0; i < CH; ++i) {
            int idx = i0 + i;
            int v = (idx < N_NODES) ? cursor[idx] : 0;
            vals[i] = sum; sum += v;
        }
    }
    __shared__ int tot[1024];
    tot[t] = sum;
    __syncthreads();
    for (int off = 1; off < 1024; off <<= 1) {
        int v = (t >= off) ? tot[t - off] : 0;
        __syncthreads();
        tot[t] += v;
        __syncthreads();
    }
    const int base = tot[t] - sum;
    if (i0 + CH <= N_NODES) {
        #pragma unroll
        for (int q = 0; q < CH / 4; ++q) {
            int4 pv = make_int4(base + vals[q * 4 + 0], base + vals[q * 4 + 1],
                                base + vals[q * 4 + 2], base + vals[q * 4 + 3]);
            *reinterpret_cast<int4*>(rowptr + i0 + q * 4) = pv;
            *reinterpret_cast<int4*>(cursor + i0 + q * 4) = pv;
        }
    } else {
        #pragma unroll
        for (int i = 0; i < CH; ++i) {
            int idx = i0 + i;
            if (idx < N_NODES) { int p = base + vals[i]; rowptr[idx] = p; cursor[idx] = p; }
        }
    }
    if (t == 0) rowptr[N_NODES] = E_EDGES;
}

// Fused edge MLP + sorted placement: 1 int atomic per edge; writes src + bf16 e_emb at sorted pos
__global__ __launch_bounds__(256) void k_edge(const float* __restrict__ ef,
        const int* __restrict__ eidx,
        const float* __restrict__ eW1, const float* __restrict__ eb1,
        const float* __restrict__ eW2, const float* __restrict__ eb2,
        int* __restrict__ cursor, int* __restrict__ srcs_s,
        unsigned short* __restrict__ esort) {
    __shared__ float efs[EPB][36];
    __shared__ float hs[EPB][17];
    __shared__ float es[EPB][17];
    __shared__ int   sidx[EPB];
    __shared__ int   didx[EPB];
    __shared__ int   poss[EPB];
    __shared__ float w1s[ED_IN][H_HID];
    __shared__ float w2s[H_HID][H_HID];
    __shared__ float b1s[H_HID];
    __shared__ float b2s[H_HID];

    const int t = threadIdx.x;
    const int e0 = blockIdx.x * EPB;     // always a full block of 64 edges

    for (int i = t; i < ED_IN * H_HID; i += 256) w1s[i / H_HID][i % H_HID] = eW1[i];
    w2s[t / H_HID][t % H_HID] = eW2[t];  // 256 entries, 256 threads
    if (t < H_HID) { b1s[t] = eb1[t]; b2s[t] = eb2[t]; }
    if (t < EPB)              sidx[t] = eidx[e0 + t];
    else if (t < 2 * EPB)     didx[t - EPB] = eidx[E_EDGES + e0 + (t - EPB)];
    #pragma unroll
    for (int i = 0; i < 2; ++i) {
        int q = t + 256 * i;
        int le = q >> 3, coff = (q & 7) * 4;
        st4(&efs[le][coff], ld4(ef + (size_t)(e0 + le) * ED_IN + coff));
    }
    __syncthreads();

    const int le = t >> 2, p = t & 3;
    {   // layer 1: 4 threads/edge, 4 hidden units each (scalar weight reads broadcast free)
        #pragma unroll
        for (int jj = 0; jj < 4; ++jj) {
            int j = p * 4 + jj;
            float acc = b1s[j];
            #pragma unroll
            for (int k = 0; k < ED_IN; ++k) acc = fmaf(efs[le][k], w1s[k][j], acc);
            hs[le][j] = gelu_exact(acc);
        }
    }
    __syncthreads();
    {   // layer 2
        #pragma unroll
        for (int cc = 0; cc < 4; ++cc) {
            int c = p * 4 + cc;
            float acc = b2s[c];
            #pragma unroll
            for (int k = 0; k < H_HID; ++k) acc = fmaf(hs[le][k], w2s[k][c], acc);
            es[le][c] = acc;
        }
    }
    __syncthreads();

    if (t < EPB) poss[t] = atomicAdd(&cursor[didx[t]], 1);
    __syncthreads();

    {   // write src + packed bf16 e_emb to sorted position (4 threads/edge, 8B each)
        int pos = poss[le];
        if (p == 0) srcs_s[pos] = sidx[le];
        ushort4 w;
        w.x = f2bf(es[le][p * 4 + 0]);
        w.y = f2bf(es[le][p * 4 + 1]);
        w.z = f2bf(es[le][p * 4 + 2]);
        w.w = f2bf(es[le][p * 4 + 3]);
        *reinterpret_cast<ushort4*>(esort + (size_t)pos * 16 + p * 4) = w;
    }
}

// CSR aggregation: one wave per node; 4 edges/iteration, 16B (8 bf16) per lane; f32 accum;
// quarter-reduce via shfl_xor(16,32); writes agg row once, as bf16.
__global__ __launch_bounds__(256) void k_agg(const unsigned short* __restrict__ xb,
        const int* __restrict__ rowptr, const int* __restrict__ srcs_s,
        const unsigned short* __restrict__ esort, unsigned short* __restrict__ aggb) {
    const int wave = threadIdx.x >> 6, lane = threadIdx.x & 63;
    const int q = lane >> 4, ql = lane & 15;       // edge slot within quad, 8-channel group
    const int n = blockIdx.x * 4 + wave;           // grid 12500 -> exactly 50000
    const int beg = rowptr[n], end = rowptr[n + 1];
    float a[8], ae[8];
    #pragma unroll
    for (int i = 0; i < 8; ++i) { a[i] = 0.f; ae[i] = 0.f; }
    for (int base = beg; base < end; base += 64) {
        const int m = min(64, end - base);
        int sv = (base + lane < end) ? srcs_s[base + lane] : 0;
        const int ng = (m + 3) >> 2;
        for (int j = 0; j < ng; ++j) {
            const int eo = 4 * j + q;
            const int s = __shfl(sv, eo);
            if (eo < m) {
                uint4 v = *reinterpret_cast<const uint4*>(xb + (size_t)s * D_IN + ql * 8);
                a[0] += bflo(v.x); a[1] += bfhi(v.x);
                a[2] += bflo(v.y); a[3] += bfhi(v.y);
                a[4] += bflo(v.z); a[5] += bfhi(v.z);
                a[6] += bflo(v.w); a[7] += bfhi(v.w);
                if (ql < 2) {
                    uint4 e = *reinterpret_cast<const uint4*>(esort + (size_t)(base + eo) * 16 + ql * 8);
                    ae[0] += bflo(e.x); ae[1] += bfhi(e.x);
                    ae[2] += bflo(e.y); ae[3] += bfhi(e.y);
                    ae[4] += bflo(e.z); ae[5] += bfhi(e.z);
                    ae[6] += bflo(e.w); ae[7] += bfhi(e.w);
                }
            }
        }
    }
    #pragma unroll
    for (int i = 0; i < 8; ++i) {
        a[i]  += __shfl_xor(a[i], 16);  a[i]  += __shfl_xor(a[i], 32);
        ae[i] += __shfl_xor(ae[i], 16); ae[i] += __shfl_xor(ae[i], 32);
    }
    if (q == 0) {
        unsigned short* ar = aggb + (size_t)n * D_CAT;
        uint4 o;
        o.x = packbf(a[0], a[1]); o.y = packbf(a[2], a[3]);
        o.z = packbf(a[4], a[5]); o.w = packbf(a[6], a[7]);
        *reinterpret_cast<uint4*>(ar + ql * 8) = o;
        if (ql < 2) {
            uint4 oe;
            oe.x = packbf(ae[0], ae[1]); oe.y = packbf(ae[2], ae[3]);
            oe.z = packbf(ae[4], ae[5]); oe.w = packbf(ae[6], ae[7]);
            *reinterpret_cast<uint4*>(ar + D_IN + ql * 8) = oe;
        }
    }
}

// h = x @ M + agg @ W1 (bf16 A operands, f32 B/accum); As stored K-major -> conflict-free b128 reads
__global__ __launch_bounds__(256) void k_gemm1(const unsigned short* __restrict__ xb,
        const unsigned short* __restrict__ aggb, const float* __restrict__ M,
        const float* __restrict__ W1, float* __restrict__ h, float* __restrict__ stats) {
    __shared__ float As[16][132];    // K-major: As[kk][row]
    __shared__ float Bs[16][132];
    __shared__ float red0[128];
    __shared__ float red1[128];
    const int t = threadIdx.x;
    const int row0 = blockIdx.x * BM;
    const int rg = t >> 4, cg = t & 15;
    float acc[8][8];
    #pragma unroll
    for (int i = 0; i < 8; ++i)
        #pragma unroll
        for (int j = 0; j < 8; ++j) acc[i][j] = 0.f;

    #pragma unroll 1
    for (int ch = 0; ch < 17; ++ch) {
        const unsigned short* Ab; const float* Bp; int lda, k0;
        if (ch < 8) { Ab = xb;   lda = D_IN;  k0 = ch * 16;       Bp = M  + k0 * 128; }
        else        { Ab = aggb; lda = D_CAT; k0 = (ch - 8) * 16; Bp = W1 + k0 * 128; }
        {   // A tile: 128 rows x 16 k, bf16 -> f32, K-major store
            int row = t >> 1, part = t & 1;
            int r = row0 + row;
            float f[8] = {0.f, 0.f, 0.f, 0.f, 0.f, 0.f, 0.f, 0.f};
            if (r < N_NODES) {
                uint4 v = *reinterpret_cast<const uint4*>(Ab + (size_t)r * lda + k0 + part * 8);
                f[0] = bflo(v.x); f[1] = bfhi(v.x); f[2] = bflo(v.y); f[3] = bfhi(v.y);
                f[4] = bflo(v.z); f[5] = bfhi(v.z); f[6] = bflo(v.w); f[7] = bfhi(v.w);
            }
            #pragma unroll
            for (int j = 0; j < 8; ++j) As[part * 8 + j][row] = f[j];
        }
        #pragma unroll
        for (int i = 0; i < 2; ++i) {        // B tile: 16x128 f32
            int qq = t + 256 * i;
            int row = qq >> 5, coff = (qq & 31) * 4;
            st4(&Bs[row][coff], ld4(Bp + row * 128 + coff));
        }
        __syncthreads();
        #pragma unroll
        for (int kk = 0; kk < 16; ++kk) {
            float4 a0 = ld4(&As[kk][rg * 8]);
            float4 a1 = ld4(&As[kk][rg * 8 + 4]);
            float4 b0 = ld4(&Bs[kk][cg * 8]);
            float4 b1v = ld4(&Bs[kk][cg * 8 + 4]);
            float av[8] = {a0.x, a0.y, a0.z, a0.w, a1.x, a1.y, a1.z, a1.w};
            float bv[8] = {b0.x, b0.y, b0.z, b0.w, b1v.x, b1v.y, b1v.z, b1v.w};
            #pragma unroll
            for (int i = 0; i < 8; ++i)
                #pragma unroll
                for (int j = 0; j < 8; ++j)
                    acc[i][j] = fmaf(av[i], bv[j], acc[i][j]);
        }
        __syncthreads();
    }

    if (t < 128) { red0[t] = 0.f; red1[t] = 0.f; }
    __syncthreads();
    float s0[8], s1[8];
    #pragma unroll
    for (int j = 0; j < 8; ++j) { s0[j] = 0.f; s1[j] = 0.f; }
    #pragma unroll
    for (int i = 0; i < 8; ++i) {
        int r = row0 + rg * 8 + i;
        if (r < N_NODES) {
            st4(h + (size_t)r * 128 + cg * 8,     make_float4(acc[i][0], acc[i][1], acc[i][2], acc[i][3]));
            st4(h + (size_t)r * 128 + cg * 8 + 4, make_float4(acc[i][4], acc[i][5], acc[i][6], acc[i][7]));
            #pragma unroll
            for (int j = 0; j < 8; ++j) { float v = acc[i][j]; s0[j] += v; s1[j] += v * v; }
        }
    }
    #pragma unroll
    for (int j = 0; j < 8; ++j) {
        atomicAdd(&red0[cg * 8 + j], s0[j]);
        atomicAdd(&red1[cg * 8 + j], s1[j]);
    }
    __syncthreads();
    if (t < 128) {
        unsafeAtomicAdd(stats + t,       red0[t]);
        unsafeAtomicAdd(stats + 128 + t, red1[t]);
    }
}

// BN affine params: a = gamma*rsqrt(var+eps), b = beta - mu*a
__global__ void k_bnparam(const float* __restrict__ stats, const float* __restrict__ gamma,
                          const float* __restrict__ beta, float* __restrict__ ab) {
    int c = threadIdx.x;
    float mu  = stats[c] * (1.0f / N_NODES);
    float var = stats[128 + c] * (1.0f / N_NODES) - mu * mu;
    float a = gamma[c] * rsqrtf(var + 1e-5f);
    ab[c] = a;
    ab[128 + c] = beta[c] - mu * a;
}

// out = GELU(a*h+b) @ W2 + b2 ; h lives in d_out (in-place safe: block reads only its own rows)
__global__ __launch_bounds__(256) void k_gemm2(const float* __restrict__ h,
        const float* __restrict__ ab, const float* __restrict__ W2,
        const float* __restrict__ b2, float* __restrict__ out) {
    __shared__ float gs[128][128];
    __shared__ float Bs[16][132];
    __shared__ float sa[128], sb[128], sc[128];
    const int t = threadIdx.x;
    const int row0 = blockIdx.x * BM;
    if (t < 128) { sa[t] = ab[t]; sb[t] = ab[128 + t]; sc[t] = b2[t]; }
    __syncthreads();
    #pragma unroll
    for (int i = 0; i < 16; ++i) {
        int q = t + 256 * i;
        int row = q >> 5, coff = (q & 31) * 4;
        int r = row0 + row;
        float4 v = make_float4(0.f, 0.f, 0.f, 0.f);
        if (r < N_NODES) v = ld4(h + (size_t)r * 128 + coff);
        v.x = gelu_exact(fmaf(sa[coff],     v.x, sb[coff]));
        v.y = gelu_exact(fmaf(sa[coff + 1], v.y, sb[coff + 1]));
        v.z = gelu_exact(fmaf(sa[coff + 2], v.z, sb[coff + 2]));
        v.w = gelu_exact(fmaf(sa[coff + 3], v.w, sb[coff + 3]));
        st4(&gs[row][coff], v);
    }
    __syncthreads();
    const int rg = t >> 4, cg = t & 15;
    float acc[8][8];
    #pragma unroll
    for (int i = 0; i < 8; ++i)
        #pragma unroll
        for (int j = 0; j < 8; ++j) acc[i][j] = 0.f;
    #pragma unroll 1
    for (int ch = 0; ch < 8; ++ch) {
        #pragma unroll
        for (int i = 0; i < 2; ++i) {
            int q = t + 256 * i;
            int row = q >> 5, coff = (q & 31) * 4;
            st4(&Bs[row][coff], ld4(W2 + (ch * 16 + row) * 128 + coff));
        }
        __syncthreads();
        #pragma unroll
        for (int kk = 0; kk < 16; ++kk) {
            int k = ch * 16 + kk;
            float a[8];
            #pragma unroll
            for (int i = 0; i < 8; ++i) a[i] = gs[rg * 8 + i][k];
            float4 b0 = ld4(&Bs[kk][cg * 8]);
            float4 b1v = ld4(&Bs[kk][cg * 8 + 4]);
            float b[8] = {b0.x, b0.y, b0.z, b0.w, b1v.x, b1v.y, b1v.z, b1v.w};
            #pragma unroll
            for (int i = 0; i < 8; ++i)
                #pragma unroll
                for (int j = 0; j < 8; ++j)
                    acc[i][j] = fmaf(a[i], b[j], acc[i][j]);
        }
        __syncthreads();
    }
    #pragma unroll
    for (int i = 0; i < 8; ++i) {
        int r = row0 + rg * 8 + i;
        if (r < N_NODES) {
            st4(out + (size_t)r * 128 + cg * 8,
                make_float4(acc[i][0] + sc[cg * 8], acc[i][1] + sc[cg * 8 + 1],
                            acc[i][2] + sc[cg * 8 + 2], acc[i][3] + sc[cg * 8 + 3]));
            st4(out + (size_t)r * 128 + cg * 8 + 4,
                make_float4(acc[i][4] + sc[cg * 8 + 4], acc[i][5] + sc[cg * 8 + 5],
                            acc[i][6] + sc[cg * 8 + 6], acc[i][7] + sc[cg * 8 + 7]));
        }
    }
}

extern "C" void kernel_launch(void* const* d_in, const int* in_sizes, int n_in,
                              void* d_out, int out_size, void* d_ws, size_t ws_size,
                              hipStream_t stream) {
    const float* x     = (const float*)d_in[0];
    const int*   eidx  = (const int*)d_in[1];
    const float* ef    = (const float*)d_in[2];
    const float* eW1   = (const float*)d_in[3];
    const float* eb1   = (const float*)d_in[4];
    const float* eW2   = (const float*)d_in[5];
    const float* eb2   = (const float*)d_in[6];
    const float* egoW  = (const float*)d_in[7];
    const float* eps   = (const float*)d_in[8];
    const float* W1    = (const float*)d_in[9];
    // d_in[10] = b1: cancels in BatchNorm (uniform shift), intentionally unused
    const float* gamma = (const float*)d_in[11];
    const float* beta  = (const float*)d_in[12];
    const float* W2    = (const float*)d_in[13];
    const float* b2    = (const float*)d_in[14];
    float* out = (float*)d_out;

    char* ws = (char*)d_ws;
    unsigned short* aggb = (unsigned short*)ws;           // N*144*2 = 14,400,000 B
    unsigned short* xb   = (unsigned short*)(ws + 14400000); // N*128*2 = 12,800,000 B
    float* stats  = (float*)(ws + 27200000);              // 1 KB
    float* M      = (float*)(ws + 27201024);              // 64 KB -> ends 27,266,560
    float* ab     = (float*)(ws + 27266560);              // 1 KB
    int*   rowptr = (int*)(ws + 27267584);                // (N+1)*4 -> pad to 200,704
    int*   cursor = (int*)(ws + 27468288);                // N*4 = 200,000
    int*   srcs_s = (int*)(ws + 27668288);                // E*4 = 3,200,000 (end ~30.9 MB)
    unsigned short* esort = (unsigned short*)d_out;       // E*16 bf16 = 25.6 MB, dead before gemm1
    float* h      = out;                                  // h staged in d_out after k_agg

    hipMemsetAsync(cursor, 0, N_NODES * 4, stream);       // deg counters
    hipMemsetAsync(stats, 0, 1024, stream);
    k_prep_M<<<dim3(128), dim3(128), 0, stream>>>(egoW, W1, eps, M);
    k_cast<<<dim3(3125), dim3(256), 0, stream>>>(x, (uint4*)xb);
    k_hist<<<dim3((E_EDGES + 255) / 256), dim3(256), 0, stream>>>(eidx + E_EDGES, cursor);
    k_scan<<<dim3(1), dim3(1024), 0, stream>>>(cursor, rowptr);
    k_edge<<<dim3(E_EDGES / EPB), dim3(256), 0, stream>>>(ef, eidx, eW1, eb1, eW2, eb2,
                                                          cursor, srcs_s, esort);
    k_agg<<<dim3(N_NODES / 4), dim3(256), 0, stream>>>(xb, rowptr, srcs_s, esort, aggb);
    k_gemm1<<<dim3((N_NODES + BM - 1) / BM), dim3(256), 0, stream>>>(xb, aggb, M, W1, h, stats);
    k_bnparam<<<dim3(1), dim3(128), 0, stream>>>(stats, gamma, beta, ab);
    k_gemm2<<<dim3((N_NODES + BM - 1) / BM), dim3(256), 0, stream>>>(h, ab, W2, b2, out);
}

// Round 6
// 302.375 us; speedup vs baseline: 1.7654x; 1.0471x over previous
//
#include <hip/hip_runtime.h>

#define N_NODES 50000
#define E_EDGES 800000
#define D_IN    128
#define ED_IN   32
#define H_HID   16
#define D_OUT2  128
#define D_CAT   144   // D_IN + H_HID
#define EPB     64    // edges per block in edge kernel (E_EDGES % EPB == 0 -> no tails)
#define BM      128   // rows per block in GEMM kernels

__device__ __forceinline__ float gelu_exact(float v) {
    return 0.5f * v * (1.0f + erff(v * 0.70710678118654752f));
}
__device__ __forceinline__ float4 ld4(const float* p) { return *reinterpret_cast<const float4*>(p); }
__device__ __forceinline__ void st4(float* p, float4 v) { *reinterpret_cast<float4*>(p) = v; }
__device__ __forceinline__ unsigned short f2bf(float f) {   // RNE bf16
    unsigned u = __float_as_uint(f);
    return (unsigned short)((u + 0x7FFFu + ((u >> 16) & 1u)) >> 16);
}
__device__ __forceinline__ float bflo(unsigned u) { return __uint_as_float(u << 16); }
__device__ __forceinline__ float bfhi(unsigned u) { return __uint_as_float(u & 0xffff0000u); }
__device__ __forceinline__ unsigned packbf(float lo, float hi) {
    return (unsigned)f2bf(lo) | ((unsigned)f2bf(hi) << 16);
}

// Block 0..127: M = (1+eps) * ego_W @ W1  [128,128]
// Block 128:    W1e = eW2 @ W1[128:144]   [16,128];  ve = eb2 @ W1[128:144]  [128]
__global__ void k_prep(const float* __restrict__ egoW, const float* __restrict__ W1,
                       const float* __restrict__ eps, const float* __restrict__ eW2,
                       const float* __restrict__ eb2,
                       float* __restrict__ M, float* __restrict__ W1e, float* __restrict__ ve) {
    int c = threadIdx.x;  // 0..127
    int d = blockIdx.x;
    if (d < 128) {
        float acc = 0.f;
        for (int j = 0; j < D_CAT; ++j)
            acc = fmaf(egoW[d * D_CAT + j], W1[j * D_OUT2 + c], acc);
        M[d * D_OUT2 + c] = (1.0f + eps[0]) * acc;
    } else {
        #pragma unroll
        for (int j = 0; j < H_HID; ++j) {
            float acc = 0.f;
            #pragma unroll
            for (int k = 0; k < H_HID; ++k)
                acc = fmaf(eW2[j * H_HID + k], W1[(D_IN + k) * D_OUT2 + c], acc);
            W1e[j * D_OUT2 + c] = acc;
        }
        float acc = 0.f;
        #pragma unroll
        for (int k = 0; k < H_HID; ++k)
            acc = fmaf(eb2[k], W1[(D_IN + k) * D_OUT2 + c], acc);
        ve[c] = acc;
    }
}

// x [N,128] f32 -> xb bf16 (packed pairs). 6.4M floats = 800000 uint4 outputs.
__global__ __launch_bounds__(256) void k_cast(const float* __restrict__ x, uint4* __restrict__ xb) {
    int i = blockIdx.x * 256 + threadIdx.x;     // grid 3125*256 == 800000 exactly
    float4 f0 = ld4(x + (size_t)i * 8);
    float4 f1 = ld4(x + (size_t)i * 8 + 4);
    uint4 o;
    o.x = packbf(f0.x, f0.y); o.y = packbf(f0.z, f0.w);
    o.z = packbf(f1.x, f1.y); o.w = packbf(f1.z, f1.w);
    xb[i] = o;
}

// degree histogram over dst
__global__ __launch_bounds__(256) void k_hist(const int* __restrict__ dst, int* __restrict__ deg) {
    int e = blockIdx.x * 256 + threadIdx.x;
    if (e < E_EDGES) atomicAdd(&deg[dst[e]], 1);
}

// single-block exclusive scan: cursor holds deg on entry; writes rowptr and rewrites cursor=prefix
__global__ __launch_bounds__(1024) void k_scan(int* __restrict__ cursor, int* __restrict__ rowptr) {
    const int t = threadIdx.x;
    const int CH = 52;                       // 1024*52 = 53248 >= 50000; 52 % 4 == 0 for int4
    const int i0 = t * CH;
    int vals[CH];
    int sum = 0;
    if (i0 + CH <= N_NODES) {
        #pragma unroll
        for (int q = 0; q < CH / 4; ++q) {
            int4 v = *reinterpret_cast<const int4*>(cursor + i0 + q * 4);
            vals[q * 4 + 0] = sum; sum += v.x;
            vals[q * 4 + 1] = sum; sum += v.y;
            vals[q * 4 + 2] = sum; sum += v.z;
            vals[q * 4 + 3] = sum; sum += v.w;
        }
    } else {
        #pragma unroll
        for (int i = 0; i < CH; ++i) {
            int idx = i0 + i;
            int v = (idx < N_NODES) ? cursor[idx] : 0;
            vals[i] = sum; sum += v;
        }
    }
    __shared__ int tot[1024];
    tot[t] = sum;
    __syncthreads();
    for (int off = 1; off < 1024; off <<= 1) {
        int v = (t >= off) ? tot[t - off] : 0;
        __syncthreads();
        tot[t] += v;
        __syncthreads();
    }
    const int base = tot[t] - sum;
    if (i0 + CH <= N_NODES) {
        #pragma unroll
        for (int q = 0; q < CH / 4; ++q) {
            int4 pv = make_int4(base + vals[q * 4 + 0], base + vals[q * 4 + 1],
                                base + vals[q * 4 + 2], base + vals[q * 4 + 3]);
            *reinterpret_cast<int4*>(rowptr + i0 + q * 4) = pv;
            *reinterpret_cast<int4*>(cursor + i0 + q * 4) = pv;
        }
    } else {
        #pragma unroll
        for (int i = 0; i < CH; ++i) {
            int idx = i0 + i;
            if (idx < N_NODES) { int p = base + vals[i]; rowptr[idx] = p; cursor[idx] = p; }
        }
    }
    if (t == 0) rowptr[N_NODES] = E_EDGES;
}

// Edge layer-1 only (layer-2 folded into gemm1 via W1e/ve): g = gelu(ef@eW1+eb1) -> bf16 at sorted pos.
// Loop-swapped MLP (float4 weight reads), atomic issued before compute, no LDS round-trip for outputs.
__global__ __launch_bounds__(256) void k_edge(const float* __restrict__ ef,
        const int* __restrict__ eidx,
        const float* __restrict__ eW1, const float* __restrict__ eb1,
        int* __restrict__ cursor, int* __restrict__ srcs_s,
        unsigned short* __restrict__ esort) {
    __shared__ float efs[EPB][36];
    __shared__ int   sidx[EPB];
    __shared__ int   didx[EPB];
    __shared__ int   poss[EPB];
    __shared__ float w1s[ED_IN][H_HID];
    __shared__ float b1s[H_HID];

    const int t = threadIdx.x;
    const int e0 = blockIdx.x * EPB;     // always a full block of 64 edges

    for (int i = t; i < ED_IN * H_HID; i += 256) w1s[i >> 4][i & 15] = eW1[i];
    if (t < H_HID) b1s[t] = eb1[t];
    if (t < EPB)              sidx[t] = eidx[e0 + t];
    else if (t < 2 * EPB)     didx[t - EPB] = eidx[E_EDGES + e0 + (t - EPB)];
    #pragma unroll
    for (int i = 0; i < 2; ++i) {
        int q = t + 256 * i;
        int le = q >> 3, coff = (q & 7) * 4;
        st4(&efs[le][coff], ld4(ef + (size_t)(e0 + le) * ED_IN + coff));
    }
    __syncthreads();

    // issue the position atomic early; latency hides under the MLP
    if (t < EPB) poss[t] = atomicAdd(&cursor[didx[t]], 1);

    const int le = t >> 2, p = t & 3;
    float a0 = b1s[p * 4 + 0], a1 = b1s[p * 4 + 1], a2 = b1s[p * 4 + 2], a3 = b1s[p * 4 + 3];
    #pragma unroll 4
    for (int k = 0; k < ED_IN; ++k) {
        float e = efs[le][k];
        float4 w = ld4(&w1s[k][p * 4]);
        a0 = fmaf(e, w.x, a0); a1 = fmaf(e, w.y, a1);
        a2 = fmaf(e, w.z, a2); a3 = fmaf(e, w.w, a3);
    }
    ushort4 wv;
    wv.x = f2bf(gelu_exact(a0));
    wv.y = f2bf(gelu_exact(a1));
    wv.z = f2bf(gelu_exact(a2));
    wv.w = f2bf(gelu_exact(a3));
    __syncthreads();                     // poss visible

    int pos = poss[le];
    if (p == 0) srcs_s[pos] = sidx[le];
    *reinterpret_cast<ushort4*>(esort + (size_t)pos * 16 + p * 4) = wv;
}

// CSR aggregation: one wave per node; 4 edges/iteration, 16B (8 bf16) per lane; f32 accum;
// quarter-reduce via shfl_xor(16,32); writes agg row once, as bf16.
__global__ __launch_bounds__(256) void k_agg(const unsigned short* __restrict__ xb,
        const int* __restrict__ rowptr, const int* __restrict__ srcs_s,
        const unsigned short* __restrict__ esort, unsigned short* __restrict__ aggb) {
    const int wave = threadIdx.x >> 6, lane = threadIdx.x & 63;
    const int q = lane >> 4, ql = lane & 15;       // edge slot within quad, 8-channel group
    const int n = blockIdx.x * 4 + wave;           // grid 12500 -> exactly 50000
    const int beg = rowptr[n], end = rowptr[n + 1];
    float a[8], ae[8];
    #pragma unroll
    for (int i = 0; i < 8; ++i) { a[i] = 0.f; ae[i] = 0.f; }
    for (int base = beg; base < end; base += 64) {
        const int m = min(64, end - base);
        int sv = (base + lane < end) ? srcs_s[base + lane] : 0;
        const int ng = (m + 3) >> 2;
        for (int j = 0; j < ng; ++j) {
            const int eo = 4 * j + q;
            const int s = __shfl(sv, eo);
            if (eo < m) {
                uint4 v = *reinterpret_cast<const uint4*>(xb + (size_t)s * D_IN + ql * 8);
                a[0] += bflo(v.x); a[1] += bfhi(v.x);
                a[2] += bflo(v.y); a[3] += bfhi(v.y);
                a[4] += bflo(v.z); a[5] += bfhi(v.z);
                a[6] += bflo(v.w); a[7] += bfhi(v.w);
                if (ql < 2) {
                    uint4 e = *reinterpret_cast<const uint4*>(esort + (size_t)(base + eo) * 16 + ql * 8);
                    ae[0] += bflo(e.x); ae[1] += bfhi(e.x);
                    ae[2] += bflo(e.y); ae[3] += bfhi(e.y);
                    ae[4] += bflo(e.z); ae[5] += bfhi(e.z);
                    ae[6] += bflo(e.w); ae[7] += bfhi(e.w);
                }
            }
        }
    }
    #pragma unroll
    for (int i = 0; i < 8; ++i) {
        a[i]  += __shfl_xor(a[i], 16);  a[i]  += __shfl_xor(a[i], 32);
        ae[i] += __shfl_xor(ae[i], 16); ae[i] += __shfl_xor(ae[i], 32);
    }
    if (q == 0) {
        unsigned short* ar = aggb + (size_t)n * D_CAT;
        uint4 o;
        o.x = packbf(a[0], a[1]); o.y = packbf(a[2], a[3]);
        o.z = packbf(a[4], a[5]); o.w = packbf(a[6], a[7]);
        *reinterpret_cast<uint4*>(ar + ql * 8) = o;
        if (ql < 2) {
            uint4 oe;
            oe.x = packbf(ae[0], ae[1]); oe.y = packbf(ae[2], ae[3]);
            oe.z = packbf(ae[4], ae[5]); oe.w = packbf(ae[6], ae[7]);
            *reinterpret_cast<uint4*>(ar + D_IN + ql * 8) = oe;
        }
    }
}

// h = x @ M + agg[:,0:128] @ W1[0:128] + agg[:,128:144] @ W1e + deg*ve  (b1 cancels in BN)
// bf16 A operands, f32 B/accum; As stored K-major -> conflict-free b128 reads
__global__ __launch_bounds__(256) void k_gemm1(const unsigned short* __restrict__ xb,
        const unsigned short* __restrict__ aggb, const float* __restrict__ M,
        const float* __restrict__ W1, const float* __restrict__ W1e,
        const float* __restrict__ ve, const int* __restrict__ rowptr,
        float* __restrict__ h, float* __restrict__ stats) {
    __shared__ float As[16][132];    // K-major: As[kk][row]
    __shared__ float Bs[16][132];
    __shared__ float red0[128];
    __shared__ float red1[128];
    __shared__ float ve_s[128];
    __shared__ int   rp_s[129];
    const int t = threadIdx.x;
    const int row0 = blockIdx.x * BM;
    const int rg = t >> 4, cg = t & 15;
    if (t < 128) ve_s[t] = ve[t];
    if (t < 129) rp_s[t] = rowptr[min(row0 + t, N_NODES)];
    float acc[8][8];
    #pragma unroll
    for (int i = 0; i < 8; ++i)
        #pragma unroll
        for (int j = 0; j < 8; ++j) acc[i][j] = 0.f;

    #pragma unroll 1
    for (int ch = 0; ch < 17; ++ch) {
        const unsigned short* Ab; const float* Bp; int lda, k0;
        if (ch < 8)       { Ab = xb;   lda = D_IN;  k0 = ch * 16;       Bp = M  + k0 * 128; }
        else if (ch < 16) { Ab = aggb; lda = D_CAT; k0 = (ch - 8) * 16; Bp = W1 + k0 * 128; }
        else              { Ab = aggb; lda = D_CAT; k0 = 128;           Bp = W1e; }
        {   // A tile: 128 rows x 16 k, bf16 -> f32, K-major store
            int row = t >> 1, part = t & 1;
            int r = row0 + row;
            float f[8] = {0.f, 0.f, 0.f, 0.f, 0.f, 0.f, 0.f, 0.f};
            if (r < N_NODES) {
                uint4 v = *reinterpret_cast<const uint4*>(Ab + (size_t)r * lda + k0 + part * 8);
                f[0] = bflo(v.x); f[1] = bfhi(v.x); f[2] = bflo(v.y); f[3] = bfhi(v.y);
                f[4] = bflo(v.z); f[5] = bfhi(v.z); f[6] = bflo(v.w); f[7] = bfhi(v.w);
            }
            #pragma unroll
            for (int j = 0; j < 8; ++j) As[part * 8 + j][row] = f[j];
        }
        #pragma unroll
        for (int i = 0; i < 2; ++i) {        // B tile: 16x128 f32
            int qq = t + 256 * i;
            int row = qq >> 5, coff = (qq & 31) * 4;
            st4(&Bs[row][coff], ld4(Bp + row * 128 + coff));
        }
        __syncthreads();
        #pragma unroll
        for (int kk = 0; kk < 16; ++kk) {
            float4 a0 = ld4(&As[kk][rg * 8]);
            float4 a1 = ld4(&As[kk][rg * 8 + 4]);
            float4 b0 = ld4(&Bs[kk][cg * 8]);
            float4 b1v = ld4(&Bs[kk][cg * 8 + 4]);
            float av[8] = {a0.x, a0.y, a0.z, a0.w, a1.x, a1.y, a1.z, a1.w};
            float bv[8] = {b0.x, b0.y, b0.z, b0.w, b1v.x, b1v.y, b1v.z, b1v.w};
            #pragma unroll
            for (int i = 0; i < 8; ++i)
                #pragma unroll
                for (int j = 0; j < 8; ++j)
                    acc[i][j] = fmaf(av[i], bv[j], acc[i][j]);
        }
        __syncthreads();
    }

    if (t < 128) { red0[t] = 0.f; red1[t] = 0.f; }
    __syncthreads();
    float s0[8], s1[8];
    #pragma unroll
    for (int j = 0; j < 8; ++j) { s0[j] = 0.f; s1[j] = 0.f; }
    #pragma unroll
    for (int i = 0; i < 8; ++i) {
        int r = row0 + rg * 8 + i;
        if (r < N_NODES) {
            float dv = (float)(rp_s[rg * 8 + i + 1] - rp_s[rg * 8 + i]);   // degree(r)
            #pragma unroll
            for (int j = 0; j < 8; ++j) acc[i][j] = fmaf(dv, ve_s[cg * 8 + j], acc[i][j]);
            st4(h + (size_t)r * 128 + cg * 8,     make_float4(acc[i][0], acc[i][1], acc[i][2], acc[i][3]));
            st4(h + (size_t)r * 128 + cg * 8 + 4, make_float4(acc[i][4], acc[i][5], acc[i][6], acc[i][7]));
            #pragma unroll
            for (int j = 0; j < 8; ++j) { float v = acc[i][j]; s0[j] += v; s1[j] += v * v; }
        }
    }
    #pragma unroll
    for (int j = 0; j < 8; ++j) {
        atomicAdd(&red0[cg * 8 + j], s0[j]);
        atomicAdd(&red1[cg * 8 + j], s1[j]);
    }
    __syncthreads();
    if (t < 128) {
        unsafeAtomicAdd(stats + t,       red0[t]);
        unsafeAtomicAdd(stats + 128 + t, red1[t]);
    }
}

// BN affine params: a = gamma*rsqrt(var+eps), b = beta - mu*a
__global__ void k_bnparam(const float* __restrict__ stats, const float* __restrict__ gamma,
                          const float* __restrict__ beta, float* __restrict__ ab) {
    int c = threadIdx.x;
    float mu  = stats[c] * (1.0f / N_NODES);
    float var = stats[128 + c] * (1.0f / N_NODES) - mu * mu;
    float a = gamma[c] * rsqrtf(var + 1e-5f);
    ab[c] = a;
    ab[128 + c] = beta[c] - mu * a;
}

// out = GELU(a*h+b) @ W2 + b2 ; h lives in d_out (in-place safe: block reads only its own rows)
__global__ __launch_bounds__(256) void k_gemm2(const float* __restrict__ h,
        const float* __restrict__ ab, const float* __restrict__ W2,
        const float* __restrict__ b2, float* __restrict__ out) {
    __shared__ float gs[128][128];
    __shared__ float Bs[16][132];
    __shared__ float sa[128], sb[128], sc[128];
    const int t = threadIdx.x;
    const int row0 = blockIdx.x * BM;
    if (t < 128) { sa[t] = ab[t]; sb[t] = ab[128 + t]; sc[t] = b2[t]; }
    __syncthreads();
    #pragma unroll
    for (int i = 0; i < 16; ++i) {
        int q = t + 256 * i;
        int row = q >> 5, coff = (q & 31) * 4;
        int r = row0 + row;
        float4 v = make_float4(0.f, 0.f, 0.f, 0.f);
        if (r < N_NODES) v = ld4(h + (size_t)r * 128 + coff);
        v.x = gelu_exact(fmaf(sa[coff],     v.x, sb[coff]));
        v.y = gelu_exact(fmaf(sa[coff + 1], v.y, sb[coff + 1]));
        v.z = gelu_exact(fmaf(sa[coff + 2], v.z, sb[coff + 2]));
        v.w = gelu_exact(fmaf(sa[coff + 3], v.w, sb[coff + 3]));
        st4(&gs[row][coff], v);
    }
    __syncthreads();
    const int rg = t >> 4, cg = t & 15;
    float acc[8][8];
    #pragma unroll
    for (int i = 0; i < 8; ++i)
        #pragma unroll
        for (int j = 0; j < 8; ++j) acc[i][j] = 0.f;
    #pragma unroll 1
    for (int ch = 0; ch < 8; ++ch) {
        #pragma unroll
        for (int i = 0; i < 2; ++i) {
            int q = t + 256 * i;
            int row = q >> 5, coff = (q & 31) * 4;
            st4(&Bs[row][coff], ld4(W2 + (ch * 16 + row) * 128 + coff));
        }
        __syncthreads();
        #pragma unroll
        for (int kk = 0; kk < 16; ++kk) {
            int k = ch * 16 + kk;
            float a[8];
            #pragma unroll
            for (int i = 0; i < 8; ++i) a[i] = gs[rg * 8 + i][k];
            float4 b0 = ld4(&Bs[kk][cg * 8]);
            float4 b1v = ld4(&Bs[kk][cg * 8 + 4]);
            float b[8] = {b0.x, b0.y, b0.z, b0.w, b1v.x, b1v.y, b1v.z, b1v.w};
            #pragma unroll
            for (int i = 0; i < 8; ++i)
                #pragma unroll
                for (int j = 0; j < 8; ++j)
                    acc[i][j] = fmaf(a[i], b[j], acc[i][j]);
        }
        __syncthreads();
    }
    #pragma unroll
    for (int i = 0; i < 8; ++i) {
        int r = row0 + rg * 8 + i;
        if (r < N_NODES) {
            st4(out + (size_t)r * 128 + cg * 8,
                make_float4(acc[i][0] + sc[cg * 8], acc[i][1] + sc[cg * 8 + 1],
                            acc[i][2] + sc[cg * 8 + 2], acc[i][3] + sc[cg * 8 + 3]));
            st4(out + (size_t)r * 128 + cg * 8 + 4,
                make_float4(acc[i][4] + sc[cg * 8 + 4], acc[i][5] + sc[cg * 8 + 5],
                            acc[i][6] + sc[cg * 8 + 6], acc[i][7] + sc[cg * 8 + 7]));
        }
    }
}

extern "C" void kernel_launch(void* const* d_in, const int* in_sizes, int n_in,
                              void* d_out, int out_size, void* d_ws, size_t ws_size,
                              hipStream_t stream) {
    const float* x     = (const float*)d_in[0];
    const int*   eidx  = (const int*)d_in[1];
    const float* ef    = (const float*)d_in[2];
    const float* eW1   = (const float*)d_in[3];
    const float* eb1   = (const float*)d_in[4];
    const float* eW2   = (const float*)d_in[5];
    const float* eb2   = (const float*)d_in[6];
    const float* egoW  = (const float*)d_in[7];
    const float* eps   = (const float*)d_in[8];
    const float* W1    = (const float*)d_in[9];
    // d_in[10] = b1: cancels in BatchNorm (uniform shift), intentionally unused
    const float* gamma = (const float*)d_in[11];
    const float* beta  = (const float*)d_in[12];
    const float* W2    = (const float*)d_in[13];
    const float* b2    = (const float*)d_in[14];
    float* out = (float*)d_out;

    char* ws = (char*)d_ws;
    unsigned short* aggb = (unsigned short*)ws;              // N*144*2 = 14,400,000 B
    unsigned short* xb   = (unsigned short*)(ws + 14400000); // N*128*2 = 12,800,000 B
    float* stats  = (float*)(ws + 27200000);                 // 1 KB
    float* M      = (float*)(ws + 27201024);                 // 64 KB -> 27,266,560
    float* W1e    = (float*)(ws + 27266560);                 // 8 KB  -> 27,274,752
    float* ve     = (float*)(ws + 27274752);                 // 512 B -> 27,275,264
    float* ab     = (float*)(ws + 27275264);                 // 1 KB  -> 27,276,288
    int*   rowptr = (int*)(ws + 27276288);                   // (N+1)*4 -> pad to 200,704
    int*   cursor = (int*)(ws + 27476992);                   // N*4 = 200,000
    int*   srcs_s = (int*)(ws + 27676992);                   // E*4 = 3,200,000 (end ~30.9 MB)
    unsigned short* esort = (unsigned short*)d_out;          // E*16 bf16 = 25.6 MB, dead before gemm1
    float* h      = out;                                     // h staged in d_out after k_agg

    hipMemsetAsync(cursor, 0, N_NODES * 4, stream);          // deg counters
    hipMemsetAsync(stats, 0, 1024, stream);
    k_prep<<<dim3(129), dim3(128), 0, stream>>>(egoW, W1, eps, eW2, eb2, M, W1e, ve);
    k_cast<<<dim3(3125), dim3(256), 0, stream>>>(x, (uint4*)xb);
    k_hist<<<dim3((E_EDGES + 255) / 256), dim3(256), 0, stream>>>(eidx + E_EDGES, cursor);
    k_scan<<<dim3(1), dim3(1024), 0, stream>>>(cursor, rowptr);
    k_edge<<<dim3(E_EDGES / EPB), dim3(256), 0, stream>>>(ef, eidx, eW1, eb1,
                                                          cursor, srcs_s, esort);
    k_agg<<<dim3(N_NODES / 4), dim3(256), 0, stream>>>(xb, rowptr, srcs_s, esort, aggb);
    k_gemm1<<<dim3((N_NODES + BM - 1) / BM), dim3(256), 0, stream>>>(xb, aggb, M, W1, W1e, ve,
                                                                     rowptr, h, stats);
    k_bnparam<<<dim3(1), dim3(128), 0, stream>>>(stats, gamma, beta, ab);
    k_gemm2<<<dim3((N_NODES + BM - 1) / BM), dim3(256), 0, stream>>>(h, ab, W2, b2, out);
}

// Round 7
// 227.822 us; speedup vs baseline: 2.3431x; 1.3272x over previous
//
#include <hip/hip_runtime.h>

#define N_NODES 50000
#define E_EDGES 800000
#define D_IN    128
#define ED_IN   32
#define H_HID   16
#define D_CAT   144
#define AGG_LD  160   // aggb row stride (144 + 16 zero pad -> K multiple of 32)
#define EPB     64
#define BM      64    // rows per block in MFMA GEMM kernels

typedef __attribute__((ext_vector_type(8))) short bf16x8;   // 8 bf16 = 4 VGPRs
typedef __attribute__((ext_vector_type(4))) float f32x4;

__device__ __forceinline__ float gelu_exact(float v) {
    return 0.5f * v * (1.0f + erff(v * 0.70710678118654752f));
}
__device__ __forceinline__ float4 ld4(const float* p) { return *reinterpret_cast<const float4*>(p); }
__device__ __forceinline__ void st4(float* p, float4 v) { *reinterpret_cast<float4*>(p) = v; }
__device__ __forceinline__ unsigned short f2bf(float f) {   // RNE bf16
    unsigned u = __float_as_uint(f);
    return (unsigned short)((u + 0x7FFFu + ((u >> 16) & 1u)) >> 16);
}
__device__ __forceinline__ float bflo(unsigned u) { return __uint_as_float(u << 16); }
__device__ __forceinline__ float bfhi(unsigned u) { return __uint_as_float(u & 0xffff0000u); }
__device__ __forceinline__ unsigned packbf(float lo, float hi) {
    return (unsigned)f2bf(lo) | ((unsigned)f2bf(hi) << 16);
}

// Builds K-major bf16 weight tables:
//  BT[c][k], k in [0,288): 0:128 = M = (1+eps)*egoW@W1 ; 128:256 = W1[0:128] ; 256:272 = W1e = eW2@W1[128:144] ; 272:288 = 0
//  W2T[c][k], k in [0,128) = W2[k][c] ;  ve[c] = eb2@W1[128:144]
__global__ void k_prep(const float* __restrict__ egoW, const float* __restrict__ W1,
                       const float* __restrict__ eps, const float* __restrict__ eW2,
                       const float* __restrict__ eb2, const float* __restrict__ W2,
                       unsigned short* __restrict__ BT, unsigned short* __restrict__ W2T,
                       float* __restrict__ ve) {
    const int c = threadIdx.x;   // 0..127
    const int d = blockIdx.x;    // 0..129
    if (d < 128) {
        float acc = 0.f;
        for (int j = 0; j < D_CAT; ++j)
            acc = fmaf(egoW[d * D_CAT + j], W1[j * 128 + c], acc);
        BT[c * 288 + d] = f2bf((1.0f + eps[0]) * acc);
    } else if (d == 128) {
        for (int j = 0; j < 128; ++j)
            BT[c * 288 + 128 + j] = f2bf(W1[j * 128 + c]);
        #pragma unroll
        for (int j = 0; j < H_HID; ++j) {
            float s = 0.f;
            #pragma unroll
            for (int k = 0; k < H_HID; ++k)
                s = fmaf(eW2[j * H_HID + k], W1[(D_IN + k) * 128 + c], s);
            BT[c * 288 + 256 + j] = f2bf(s);
        }
        #pragma unroll
        for (int j = 272; j < 288; ++j) BT[c * 288 + j] = 0;
        float s = 0.f;
        #pragma unroll
        for (int k = 0; k < H_HID; ++k)
            s = fmaf(eb2[k], W1[(D_IN + k) * 128 + c], s);
        ve[c] = s;
    } else {
        for (int k = 0; k < 128; ++k)
            W2T[c * 128 + k] = f2bf(W2[k * 128 + c]);
    }
}

// x [N,128] f32 -> xb bf16 packed
__global__ __launch_bounds__(256) void k_cast(const float* __restrict__ x, uint4* __restrict__ xb) {
    int i = blockIdx.x * 256 + threadIdx.x;     // 3125*256 == 800000 exactly
    float4 f0 = ld4(x + (size_t)i * 8);
    float4 f1 = ld4(x + (size_t)i * 8 + 4);
    uint4 o;
    o.x = packbf(f0.x, f0.y); o.y = packbf(f0.z, f0.w);
    o.z = packbf(f1.x, f1.y); o.w = packbf(f1.z, f1.w);
    xb[i] = o;
}

// degree histogram over dst
__global__ __launch_bounds__(256) void k_hist(const int* __restrict__ dst, int* __restrict__ deg) {
    int e = blockIdx.x * 256 + threadIdx.x;
    if (e < E_EDGES) atomicAdd(&deg[dst[e]], 1);
}

// single-block exclusive scan: cursor=deg on entry; writes rowptr, cursor=prefix
__global__ __launch_bounds__(1024) void k_scan(int* __restrict__ cursor, int* __restrict__ rowptr) {
    const int t = threadIdx.x;
    const int CH = 52;
    const int i0 = t * CH;
    int vals[CH];
    int sum = 0;
    if (i0 + CH <= N_NODES) {
        #pragma unroll
        for (int q = 0; q < CH / 4; ++q) {
            int4 v = *reinterpret_cast<const int4*>(cursor + i0 + q * 4);
            vals[q * 4 + 0] = sum; sum += v.x;
            vals[q * 4 + 1] = sum; sum += v.y;
            vals[q * 4 + 2] = sum; sum += v.z;
            vals[q * 4 + 3] = sum; sum += v.w;
        }
    } else {
        #pragma unroll
        for (int i = 0; i < CH; ++i) {
            int idx = i0 + i;
            int v = (idx < N_NODES) ? cursor[idx] : 0;
            vals[i] = sum; sum += v;
        }
    }
    __shared__ int tot[1024];
    tot[t] = sum;
    __syncthreads();
    for (int off = 1; off < 1024; off <<= 1) {
        int v = (t >= off) ? tot[t - off] : 0;
        __syncthreads();
        tot[t] += v;
        __syncthreads();
    }
    const int base = tot[t] - sum;
    if (i0 + CH <= N_NODES) {
        #pragma unroll
        for (int q = 0; q < CH / 4; ++q) {
            int4 pv = make_int4(base + vals[q * 4 + 0], base + vals[q * 4 + 1],
                                base + vals[q * 4 + 2], base + vals[q * 4 + 3]);
            *reinterpret_cast<int4*>(rowptr + i0 + q * 4) = pv;
            *reinterpret_cast<int4*>(cursor + i0 + q * 4) = pv;
        }
    } else {
        #pragma unroll
        for (int i = 0; i < CH; ++i) {
            int idx = i0 + i;
            if (idx < N_NODES) { int p = base + vals[i]; rowptr[idx] = p; cursor[idx] = p; }
        }
    }
    if (t == 0) rowptr[N_NODES] = E_EDGES;
}

// Edge layer-1 only: g = gelu(ef@eW1+eb1) -> bf16 at sorted pos
__global__ __launch_bounds__(256) void k_edge(const float* __restrict__ ef,
        const int* __restrict__ eidx,
        const float* __restrict__ eW1, const float* __restrict__ eb1,
        int* __restrict__ cursor, int* __restrict__ srcs_s,
        unsigned short* __restrict__ esort) {
    __shared__ float efs[EPB][36];
    __shared__ int   sidx[EPB];
    __shared__ int   didx[EPB];
    __shared__ int   poss[EPB];
    __shared__ float w1s[ED_IN][H_HID];
    __shared__ float b1s[H_HID];

    const int t = threadIdx.x;
    const int e0 = blockIdx.x * EPB;

    for (int i = t; i < ED_IN * H_HID; i += 256) w1s[i >> 4][i & 15] = eW1[i];
    if (t < H_HID) b1s[t] = eb1[t];
    if (t < EPB)              sidx[t] = eidx[e0 + t];
    else if (t < 2 * EPB)     didx[t - EPB] = eidx[E_EDGES + e0 + (t - EPB)];
    #pragma unroll
    for (int i = 0; i < 2; ++i) {
        int q = t + 256 * i;
        int le = q >> 3, coff = (q & 7) * 4;
        st4(&efs[le][coff], ld4(ef + (size_t)(e0 + le) * ED_IN + coff));
    }
    __syncthreads();

    if (t < EPB) poss[t] = atomicAdd(&cursor[didx[t]], 1);

    const int le = t >> 2, p = t & 3;
    float a0 = b1s[p * 4 + 0], a1 = b1s[p * 4 + 1], a2 = b1s[p * 4 + 2], a3 = b1s[p * 4 + 3];
    #pragma unroll 4
    for (int k = 0; k < ED_IN; ++k) {
        float e = efs[le][k];
        float4 w = ld4(&w1s[k][p * 4]);
        a0 = fmaf(e, w.x, a0); a1 = fmaf(e, w.y, a1);
        a2 = fmaf(e, w.z, a2); a3 = fmaf(e, w.w, a3);
    }
    ushort4 wv;
    wv.x = f2bf(gelu_exact(a0));
    wv.y = f2bf(gelu_exact(a1));
    wv.z = f2bf(gelu_exact(a2));
    wv.w = f2bf(gelu_exact(a3));
    __syncthreads();

    int pos = poss[le];
    if (p == 0) srcs_s[pos] = sidx[le];
    *reinterpret_cast<ushort4*>(esort + (size_t)pos * 16 + p * 4) = wv;
}

// CSR aggregation -> aggb rows [x(128) | g(16) | zeros(16)] bf16, stride 160
__global__ __launch_bounds__(256) void k_agg(const unsigned short* __restrict__ xb,
        const int* __restrict__ rowptr, const int* __restrict__ srcs_s,
        const unsigned short* __restrict__ esort, unsigned short* __restrict__ aggb) {
    const int wave = threadIdx.x >> 6, lane = threadIdx.x & 63;
    const int q = lane >> 4, ql = lane & 15;
    const int n = blockIdx.x * 4 + wave;
    const int beg = rowptr[n], end = rowptr[n + 1];
    float a[8], ae[8];
    #pragma unroll
    for (int i = 0; i < 8; ++i) { a[i] = 0.f; ae[i] = 0.f; }
    for (int base = beg; base < end; base += 64) {
        const int m = min(64, end - base);
        int sv = (base + lane < end) ? srcs_s[base + lane] : 0;
        const int ng = (m + 3) >> 2;
        for (int j = 0; j < ng; ++j) {
            const int eo = 4 * j + q;
            const int s = __shfl(sv, eo);
            if (eo < m) {
                uint4 v = *reinterpret_cast<const uint4*>(xb + (size_t)s * D_IN + ql * 8);
                a[0] += bflo(v.x); a[1] += bfhi(v.x);
                a[2] += bflo(v.y); a[3] += bfhi(v.y);
                a[4] += bflo(v.z); a[5] += bfhi(v.z);
                a[6] += bflo(v.w); a[7] += bfhi(v.w);
                if (ql < 2) {
                    uint4 e = *reinterpret_cast<const uint4*>(esort + (size_t)(base + eo) * 16 + ql * 8);
                    ae[0] += bflo(e.x); ae[1] += bfhi(e.x);
                    ae[2] += bflo(e.y); ae[3] += bfhi(e.y);
                    ae[4] += bflo(e.z); ae[5] += bfhi(e.z);
                    ae[6] += bflo(e.w); ae[7] += bfhi(e.w);
                }
            }
        }
    }
    #pragma unroll
    for (int i = 0; i < 8; ++i) {
        a[i]  += __shfl_xor(a[i], 16);  a[i]  += __shfl_xor(a[i], 32);
        ae[i] += __shfl_xor(ae[i], 16); ae[i] += __shfl_xor(ae[i], 32);
    }
    if (q == 0) {
        unsigned short* ar = aggb + (size_t)n * AGG_LD;
        uint4 o;
        o.x = packbf(a[0], a[1]); o.y = packbf(a[2], a[3]);
        o.z = packbf(a[4], a[5]); o.w = packbf(a[6], a[7]);
        *reinterpret_cast<uint4*>(ar + ql * 8) = o;
        if (ql < 2) {
            uint4 oe;
            oe.x = packbf(ae[0], ae[1]); oe.y = packbf(ae[2], ae[3]);
            oe.z = packbf(ae[4], ae[5]); oe.w = packbf(ae[6], ae[7]);
            *reinterpret_cast<uint4*>(ar + D_IN + ql * 8) = oe;
            uint4 z = make_uint4(0u, 0u, 0u, 0u);                 // K-pad
            *reinterpret_cast<uint4*>(ar + D_CAT + ql * 8) = z;
        }
    }
}

// MFMA GEMM1: h[N,128] = [xb | aggb] @ BT^T + deg*ve ; col stats
// wave w: rows [w*16, w*16+16) x 128 cols; C layout col=l&15, row=(l>>4)*4+i
__global__ __launch_bounds__(256) void k_gemm1(const unsigned short* __restrict__ xb,
        const unsigned short* __restrict__ aggb, const unsigned short* __restrict__ BT,
        const float* __restrict__ ve, const int* __restrict__ rowptr,
        float* __restrict__ h, float* __restrict__ stats) {
    __shared__ short As[64][40];     // stride 80B: 16B aligned, uniform banks
    __shared__ short Bs[128][40];
    __shared__ float red0[128], red1[128];
    __shared__ float ve_s[128];
    __shared__ int   rp_s[65];
    const int t = threadIdx.x;
    const int row0 = blockIdx.x * BM;
    if (t < 128) { ve_s[t] = ve[t]; red0[t] = 0.f; red1[t] = 0.f; }
    if (t < 65) rp_s[t] = rowptr[min(row0 + t, N_NODES)];
    const int w = t >> 6, l = t & 63;
    const int arow = w * 16 + (l & 15);
    const int koff = (l >> 4) * 8;
    f32x4 acc[8];
    #pragma unroll
    for (int ct = 0; ct < 8; ++ct) acc[ct] = (f32x4){0.f, 0.f, 0.f, 0.f};

    #pragma unroll 1
    for (int ch = 0; ch < 9; ++ch) {
        const unsigned short* Ab; int lda, k0, kb;
        if (ch < 4) { Ab = xb;   lda = D_IN;   k0 = ch * 32;       kb = ch * 32; }
        else        { Ab = aggb; lda = AGG_LD; k0 = (ch - 4) * 32; kb = 128 + (ch - 4) * 32; }
        {   // A tile 64x32
            int row = t >> 2, slot = t & 3;
            int r = row0 + row;
            uint4 v = make_uint4(0u, 0u, 0u, 0u);
            if (r < N_NODES) v = *reinterpret_cast<const uint4*>(Ab + (size_t)r * lda + k0 + slot * 8);
            *reinterpret_cast<uint4*>(&As[row][slot * 8]) = v;
        }
        #pragma unroll
        for (int i = 0; i < 2; ++i) {    // B tile 128x32 (K-major from BT)
            int qq = t + 256 * i;
            int row = qq >> 2, slot = qq & 3;
            *reinterpret_cast<uint4*>(&Bs[row][slot * 8]) =
                *reinterpret_cast<const uint4*>(BT + row * 288 + kb + slot * 8);
        }
        __syncthreads();
        bf16x8 af = *reinterpret_cast<const bf16x8*>(&As[arow][koff]);
        #pragma unroll
        for (int ct = 0; ct < 8; ++ct) {
            bf16x8 bfv = *reinterpret_cast<const bf16x8*>(&Bs[ct * 16 + (l & 15)][koff]);
            acc[ct] = __builtin_amdgcn_mfma_f32_16x16x32_bf16(af, bfv, acc[ct], 0, 0, 0);
        }
        __syncthreads();
    }

    #pragma unroll
    for (int ct = 0; ct < 8; ++ct) {
        const int col = ct * 16 + (l & 15);
        float cs0 = 0.f, cs1 = 0.f;
        #pragma unroll
        for (int i = 0; i < 4; ++i) {
            int lr = w * 16 + (l >> 4) * 4 + i;
            int r = row0 + lr;
            float dv = (float)(rp_s[lr + 1] - rp_s[lr]);
            float v = acc[ct][i] + dv * ve_s[col];
            if (r < N_NODES) { h[(size_t)r * 128 + col] = v; cs0 += v; cs1 += v * v; }
        }
        cs0 += __shfl_xor(cs0, 16); cs0 += __shfl_xor(cs0, 32);
        cs1 += __shfl_xor(cs1, 16); cs1 += __shfl_xor(cs1, 32);
        if (l < 16) { atomicAdd(&red0[col], cs0); atomicAdd(&red1[col], cs1); }
    }
    __syncthreads();
    if (t < 128) {
        unsafeAtomicAdd(stats + t,       red0[t]);
        unsafeAtomicAdd(stats + 128 + t, red1[t]);
    }
}

// BN affine params: a = gamma*rsqrt(var+eps), b = beta - mu*a
__global__ void k_bnparam(const float* __restrict__ stats, const float* __restrict__ gamma,
                          const float* __restrict__ beta, float* __restrict__ ab) {
    int c = threadIdx.x;
    float mu  = stats[c] * (1.0f / N_NODES);
    float var = stats[128 + c] * (1.0f / N_NODES) - mu * mu;
    float a = gamma[c] * rsqrtf(var + 1e-5f);
    ab[c] = a;
    ab[128 + c] = beta[c] - mu * a;
}

// MFMA GEMM2: out = GELU(a*h+b) @ W2 + b2 ; in-place in d_out (block reads only its own rows)
__global__ __launch_bounds__(256) void k_gemm2(const float* __restrict__ h,
        const float* __restrict__ ab, const unsigned short* __restrict__ W2T,
        const float* __restrict__ b2, float* __restrict__ out) {
    __shared__ short As[64][136];    // full K=128 staged once; stride 272B
    __shared__ short Bs[128][40];
    __shared__ float sa[128], sb[128], sc[128];
    const int t = threadIdx.x;
    const int row0 = blockIdx.x * BM;
    if (t < 128) { sa[t] = ab[t]; sb[t] = ab[128 + t]; sc[t] = b2[t]; }
    __syncthreads();
    {   // stage A: affine + GELU -> bf16
        int row = t >> 2, q = t & 3;
        int r = row0 + row;
        #pragma unroll
        for (int i = 0; i < 8; ++i) {
            int c = q * 32 + i * 4;
            float4 v = (r < N_NODES) ? ld4(h + (size_t)r * 128 + c) : make_float4(0.f, 0.f, 0.f, 0.f);
            ushort4 pw;
            pw.x = f2bf(gelu_exact(fmaf(sa[c],     v.x, sb[c])));
            pw.y = f2bf(gelu_exact(fmaf(sa[c + 1], v.y, sb[c + 1])));
            pw.z = f2bf(gelu_exact(fmaf(sa[c + 2], v.z, sb[c + 2])));
            pw.w = f2bf(gelu_exact(fmaf(sa[c + 3], v.w, sb[c + 3])));
            *reinterpret_cast<ushort4*>(&As[row][c]) = pw;
        }
    }
    const int w = t >> 6, l = t & 63;
    const int arow = w * 16 + (l & 15);
    const int koff = (l >> 4) * 8;
    f32x4 acc[8];
    #pragma unroll
    for (int ct = 0; ct < 8; ++ct) acc[ct] = (f32x4){0.f, 0.f, 0.f, 0.f};

    #pragma unroll 1
    for (int ks = 0; ks < 4; ++ks) {
        #pragma unroll
        for (int i = 0; i < 2; ++i) {    // B tile 128x32 from W2T
            int qq = t + 256 * i;
            int row = qq >> 2, slot = qq & 3;
            *reinterpret_cast<uint4*>(&Bs[row][slot * 8]) =
                *reinterpret_cast<const uint4*>(W2T + row * 128 + ks * 32 + slot * 8);
        }
        __syncthreads();
        bf16x8 af = *reinterpret_cast<const bf16x8*>(&As[arow][ks * 32 + koff]);
        #pragma unroll
        for (int ct = 0; ct < 8; ++ct) {
            bf16x8 bfv = *reinterpret_cast<const bf16x8*>(&Bs[ct * 16 + (l & 15)][koff]);
            acc[ct] = __builtin_amdgcn_mfma_f32_16x16x32_bf16(af, bfv, acc[ct], 0, 0, 0);
        }
        __syncthreads();
    }
    #pragma unroll
    for (int ct = 0; ct < 8; ++ct) {
        const int col = ct * 16 + (l & 15);
        #pragma unroll
        for (int i = 0; i < 4; ++i) {
            int r = row0 + w * 16 + (l >> 4) * 4 + i;
            if (r < N_NODES) out[(size_t)r * 128 + col] = acc[ct][i] + sc[col];
        }
    }
}

extern "C" void kernel_launch(void* const* d_in, const int* in_sizes, int n_in,
                              void* d_out, int out_size, void* d_ws, size_t ws_size,
                              hipStream_t stream) {
    const float* x     = (const float*)d_in[0];
    const int*   eidx  = (const int*)d_in[1];
    const float* ef    = (const float*)d_in[2];
    const float* eW1   = (const float*)d_in[3];
    const float* eb1   = (const float*)d_in[4];
    const float* eW2   = (const float*)d_in[5];
    const float* eb2   = (const float*)d_in[6];
    const float* egoW  = (const float*)d_in[7];
    const float* eps   = (const float*)d_in[8];
    const float* W1    = (const float*)d_in[9];
    // d_in[10] = b1: cancels in BatchNorm (uniform shift), intentionally unused
    const float* gamma = (const float*)d_in[11];
    const float* beta  = (const float*)d_in[12];
    const float* W2    = (const float*)d_in[13];
    const float* b2    = (const float*)d_in[14];
    float* out = (float*)d_out;

    char* ws = (char*)d_ws;
    unsigned short* aggb = (unsigned short*)ws;              // N*160*2 = 16,000,000
    unsigned short* xb   = (unsigned short*)(ws + 16000000); // N*128*2 = 12,800,000 -> 28,800,000
    float* stats  = (float*)(ws + 28800000);                 // 1 KB   -> 28,801,024
    unsigned short* BT  = (unsigned short*)(ws + 28801024);  // 128*288*2 = 73,728 -> 28,874,752
    unsigned short* W2T = (unsigned short*)(ws + 28874752);  // 128*128*2 = 32,768 -> 28,907,520
    float* ve     = (float*)(ws + 28907520);                 // 512 B  -> 28,908,032
    float* ab     = (float*)(ws + 28908032);                 // 1 KB   -> 28,909,056
    int*   rowptr = (int*)(ws + 28909056);                   // pad to 200,704 -> 29,109,760
    int*   cursor = (int*)(ws + 29109760);                   // 200,000 -> 29,309,760
    int*   srcs_s = (int*)(ws + 29309760);                   // 3,200,000 -> 32,509,760
    unsigned short* esort = (unsigned short*)d_out;          // E*16 bf16 = 25.6 MB, dead before gemm1
    float* h      = out;                                     // h staged in d_out after k_agg

    hipMemsetAsync(cursor, 0, N_NODES * 4, stream);
    hipMemsetAsync(stats, 0, 1024, stream);
    k_prep<<<dim3(130), dim3(128), 0, stream>>>(egoW, W1, eps, eW2, eb2, W2, BT, W2T, ve);
    k_cast<<<dim3(3125), dim3(256), 0, stream>>>(x, (uint4*)xb);
    k_hist<<<dim3((E_EDGES + 255) / 256), dim3(256), 0, stream>>>(eidx + E_EDGES, cursor);
    k_scan<<<dim3(1), dim3(1024), 0, stream>>>(cursor, rowptr);
    k_edge<<<dim3(E_EDGES / EPB), dim3(256), 0, stream>>>(ef, eidx, eW1, eb1,
                                                          cursor, srcs_s, esort);
    k_agg<<<dim3(N_NODES / 4), dim3(256), 0, stream>>>(xb, rowptr, srcs_s, esort, aggb);
    k_gemm1<<<dim3((N_NODES + BM - 1) / BM), dim3(256), 0, stream>>>(xb, aggb, BT, ve,
                                                                     rowptr, h, stats);
    k_bnparam<<<dim3(1), dim3(128), 0, stream>>>(stats, gamma, beta, ab);
    k_gemm2<<<dim3((N_NODES + BM - 1) / BM), dim3(256), 0, stream>>>(h, ab, W2T, b2, out);
}